// Round 1
// baseline (1093.971 us; speedup 1.0000x reference)
//
#include <hip/hip_runtime.h>
#include <hip/hip_bf16.h>
#include <math.h>

// ---------------------------------------------------------------------------
// Autoformer encoder layer, MI355X (gfx950).
// B=4, L=4096, D=512, H=8, dk=64, F=2048, MA=25, top_k=8.
// All GEMMs in fp16 MFMA (16x16x32_f16), fp32 accumulate.
// ---------------------------------------------------------------------------

typedef _Float16 half8_t __attribute__((ext_vector_type(8)));
typedef _Float16 half4_t __attribute__((ext_vector_type(4)));
typedef float    f32x4_t __attribute__((ext_vector_type(4)));

__device__ __forceinline__ void gl_lds16(const _Float16* src, _Float16* dst) {
  __builtin_amdgcn_global_load_lds(
      (const __attribute__((address_space(1))) unsigned int*)(const void*)src,
      (__attribute__((address_space(3))) unsigned int*)(void*)dst, 16, 0, 0);
}

// ---------------------------------------------------------------------------
// Generic fp16 GEMM:  out[M,N] = A[M,K] @ Bt[N,K]^T + bias, optional GELU.
// 128x128 tile, BK=64, 256 threads (4 waves, 2x2), XOR-swizzled LDS.
// ---------------------------------------------------------------------------
template<bool OUT16, bool DOGELU>
__global__ __launch_bounds__(256) void gemm_f16k(
    const _Float16* __restrict__ A, const _Float16* __restrict__ Bt,
    const float* __restrict__ bias, void* __restrict__ outp,
    int M, int N, int K)
{
  __shared__ _Float16 As[128 * 64];
  __shared__ _Float16 Bs[128 * 64];
  const int tid = threadIdx.x, lane = tid & 63, w = tid >> 6;
  const int wr = w >> 1, wc = w & 1;
  const int m0 = blockIdx.x * 128, n0 = blockIdx.y * 128;

  f32x4_t acc[4][4];
  #pragma unroll
  for (int i = 0; i < 4; ++i)
    #pragma unroll
    for (int j = 0; j < 4; ++j) acc[i][j] = (f32x4_t){0.f, 0.f, 0.f, 0.f};

  const _Float16* Ab = A + (size_t)m0 * K;
  const _Float16* Bb = Bt + (size_t)n0 * K;

  for (int k0 = 0; k0 < K; k0 += 64) {
    // stage A tile (128 rows x 64 halfs), swizzled source so linear LDS
    // ends up with phys_slot = logical_slot ^ (row&7)
    #pragma unroll
    for (int q = 0; q < 4; ++q) {
      int off = ((w << 2) + q) << 10;            // byte offset of wave-issue
      int row = (off >> 7) + (lane >> 3);
      int sl  = (lane & 7) ^ (row & 7);          // logical k-slot for this phys slot
      gl_lds16(Ab + (size_t)row * K + k0 + (sl << 3), As + (off >> 1));
    }
    #pragma unroll
    for (int q = 0; q < 4; ++q) {
      int off = ((w << 2) + q) << 10;
      int row = (off >> 7) + (lane >> 3);
      int sl  = (lane & 7) ^ (row & 7);
      gl_lds16(Bb + (size_t)row * K + k0 + (sl << 3), Bs + (off >> 1));
    }
    __syncthreads();

    #pragma unroll
    for (int kk = 0; kk < 2; ++kk) {
      half8_t af[4], bf[4];
      #pragma unroll
      for (int mi = 0; mi < 4; ++mi) {
        int row = wr * 64 + mi * 16 + (lane & 15);
        int sl  = ((kk << 2) + (lane >> 4)) ^ (row & 7);
        af[mi] = *(const half8_t*)(As + row * 64 + (sl << 3));
      }
      #pragma unroll
      for (int ni = 0; ni < 4; ++ni) {
        int row = wc * 64 + ni * 16 + (lane & 15);
        int sl  = ((kk << 2) + (lane >> 4)) ^ (row & 7);
        bf[ni] = *(const half8_t*)(Bs + row * 64 + (sl << 3));
      }
      #pragma unroll
      for (int mi = 0; mi < 4; ++mi)
        #pragma unroll
        for (int ni = 0; ni < 4; ++ni)
          acc[mi][ni] = __builtin_amdgcn_mfma_f32_16x16x32_f16(
              af[mi], bf[ni], acc[mi][ni], 0, 0, 0);
    }
    __syncthreads();
  }

  float bvv[4];
  #pragma unroll
  for (int ni = 0; ni < 4; ++ni)
    bvv[ni] = bias[n0 + wc * 64 + ni * 16 + (lane & 15)];

  #pragma unroll
  for (int mi = 0; mi < 4; ++mi) {
    int rbase = m0 + wr * 64 + mi * 16 + ((lane >> 4) << 2);
    #pragma unroll
    for (int ni = 0; ni < 4; ++ni) {
      int col = n0 + wc * 64 + ni * 16 + (lane & 15);
      #pragma unroll
      for (int r = 0; r < 4; ++r) {
        float v = acc[mi][ni][r] + bvv[ni];
        if (DOGELU) v = 0.5f * v * (1.f + erff(v * 0.70710678118654752f));
        size_t idx = (size_t)(rbase + r) * N + col;
        if (OUT16) ((_Float16*)outp)[idx] = (_Float16)v;
        else       ((float*)outp)[idx]    = v;
      }
    }
  }
}

// ---------------------------------------------------------------------------
// Autocorrelation: corr[b,h,tau] = sum_t Q[b,h,(t+tau)%L,:] . K[b,h,t,:]
// Per block: one (b,h) and one 64-row Q block; loops all 64 K blocks,
// computes 64x64 Gram tile via MFMA, reduces circular diagonals into LDS.
// ---------------------------------------------------------------------------
__global__ __launch_bounds__(256) void corr_gram(
    const _Float16* __restrict__ Q, const _Float16* __restrict__ Kt,
    float* __restrict__ corr)
{
  __shared__ _Float16 Qs[64 * 64];
  __shared__ _Float16 Ks[64 * 64];
  __shared__ float Gs[64 * 65];     // +1 pad to kill ds_write conflicts
  __shared__ float cl[4096];
  const int tid = threadIdx.x, lane = tid & 63, w = tid >> 6;
  const int I = blockIdx.x, h = blockIdx.y, b = blockIdx.z;

  for (int i = tid; i < 4096; i += 256) cl[i] = 0.f;

  const size_t baseQ = ((size_t)b * 4096 + (size_t)I * 64) * 512 + h * 64;
  #pragma unroll
  for (int q = 0; q < 2; ++q) {
    int off = ((w << 1) + q) << 10;
    int row = (off >> 7) + (lane >> 3);
    int sl  = (lane & 7) ^ (row & 7);
    gl_lds16(Q + baseQ + (size_t)row * 512 + (sl << 3), Qs + (off >> 1));
  }

  for (int J = 0; J < 64; ++J) {
    const size_t baseK = ((size_t)b * 4096 + (size_t)J * 64) * 512 + h * 64;
    #pragma unroll
    for (int q = 0; q < 2; ++q) {
      int off = ((w << 1) + q) << 10;
      int row = (off >> 7) + (lane >> 3);
      int sl  = (lane & 7) ^ (row & 7);
      gl_lds16(Kt + baseK + (size_t)row * 512 + (sl << 3), Ks + (off >> 1));
    }
    __syncthreads();                       // staging done, Gs free (prev diag done)

    half8_t qf[2];
    #pragma unroll
    for (int kk = 0; kk < 2; ++kk) {
      int row = (w << 4) + (lane & 15);
      int sl  = ((kk << 2) + (lane >> 4)) ^ (row & 7);
      qf[kk] = *(const half8_t*)(Qs + row * 64 + (sl << 3));
    }
    f32x4_t accv[4];
    #pragma unroll
    for (int ni = 0; ni < 4; ++ni) {
      f32x4_t a = (f32x4_t){0.f, 0.f, 0.f, 0.f};
      #pragma unroll
      for (int kk = 0; kk < 2; ++kk) {
        int row = (ni << 4) + (lane & 15);
        int sl  = ((kk << 2) + (lane >> 4)) ^ (row & 7);
        half8_t kf = *(const half8_t*)(Ks + row * 64 + (sl << 3));
        a = __builtin_amdgcn_mfma_f32_16x16x32_f16(qf[kk], kf, a, 0, 0, 0);
      }
      accv[ni] = a;
    }
    // wave w wrote G rows [16w,16w+16)
    #pragma unroll
    for (int ni = 0; ni < 4; ++ni)
      #pragma unroll
      for (int r = 0; r < 4; ++r) {
        int il = (w << 4) + ((lane >> 4) << 2) + r;
        int jl = (ni << 4) + (lane & 15);
        Gs[il * 65 + jl] = accv[ni][r];
      }
    __syncthreads();

    // diagonal reduce: delta = i-j in [-63,63]; 2 threads per diagonal
    if (tid < 254) {
      int d  = (tid >> 1) - 63;
      int hf = tid & 1;
      int j0 = d < 0 ? -d : 0;
      int j1 = d > 0 ? 64 - d : 64;
      int mid = j0 + ((j1 - j0 + 1) >> 1);
      int ja = hf ? mid : j0;
      int jb = hf ? j1 : mid;
      float s = 0.f;
      for (int j = ja; j < jb; ++j) s += Gs[(j + d) * 65 + j];
      int tau = (((I - J) << 6) + d) & 4095;
      atomicAdd(&cl[tau], s);
    }
    __syncthreads();
  }

  float* cg = corr + ((size_t)(b * 8 + h)) * 4096;
  for (int i = tid; i < 4096; i += 256) atomicAdd(&cg[i], cl[i]);
}

// ---------------------------------------------------------------------------
// Top-8 + softmax per (b,h). Tie-break: lowest index (matches stable top_k).
// ---------------------------------------------------------------------------
__global__ __launch_bounds__(256) void topk_softmax(
    const float* __restrict__ corr, float* __restrict__ tw, int* __restrict__ ti)
{
  __shared__ float vals[4096];
  __shared__ float wvv[4]; __shared__ int wii[4];
  __shared__ float rv[8]; __shared__ int ri[8];
  const int tid = threadIdx.x;
  const int bh = blockIdx.x;
  const float* c = corr + (size_t)bh * 4096;
  for (int i = tid; i < 4096; i += 256) vals[i] = c[i];
  __syncthreads();

  for (int it = 0; it < 8; ++it) {
    float bv = -3.4e38f; int bi = 1 << 30;
    for (int i = tid; i < 4096; i += 256) {
      float v = vals[i];
      if (v > bv) { bv = v; bi = i; }
    }
    #pragma unroll
    for (int o = 32; o > 0; o >>= 1) {
      float ov = __shfl_down(bv, o);
      int   oi = __shfl_down(bi, o);
      if (ov > bv || (ov == bv && oi < bi)) { bv = ov; bi = oi; }
    }
    if ((tid & 63) == 0) { wvv[tid >> 6] = bv; wii[tid >> 6] = bi; }
    __syncthreads();
    if (tid == 0) {
      for (int k = 1; k < 4; ++k)
        if (wvv[k] > bv || (wvv[k] == bv && wii[k] < bi)) { bv = wvv[k]; bi = wii[k]; }
      rv[it] = bv; ri[it] = bi; vals[bi] = -3.4e38f;
    }
    __syncthreads();
  }

  if (tid == 0) {
    float m = rv[0] * (1.f / 64.f);          // corr_mean = corr/dk; rv[0] is max
    float e[8]; float s = 0.f;
    for (int k = 0; k < 8; ++k) { e[k] = expf(rv[k] * (1.f / 64.f) - m); s += e[k]; }
    float inv = 1.f / s;
    for (int k = 0; k < 8; ++k) { tw[bh * 8 + k] = e[k] * inv; ti[bh * 8 + k] = ri[k]; }
  }
}

// ---------------------------------------------------------------------------
// out[b,l,h*64+d] = sum_k tw[k] * V[b,(l+ti[k])%L, h*64+d], stored fp16.
// ---------------------------------------------------------------------------
__global__ __launch_bounds__(256) void gather_attn(
    const float* __restrict__ V, const float* __restrict__ tw,
    const int* __restrict__ ti, _Float16* __restrict__ outp)
{
  const int tid = threadIdx.x;
  const int d4 = tid & 127;
  const int r  = (blockIdx.x << 1) + (tid >> 7);
  const int b  = r >> 12, l = r & 4095;
  const int h  = d4 >> 4;
  const float* w8 = tw + (((b << 3) + h) << 3);
  const int*   i8 = ti + (((b << 3) + h) << 3);
  f32x4_t acc = (f32x4_t){0.f, 0.f, 0.f, 0.f};
  #pragma unroll
  for (int k = 0; k < 8; ++k) {
    int ls = (l + i8[k]) & 4095;
    f32x4_t v = *(const f32x4_t*)(V + (((size_t)(b << 12) + ls) << 9) + (d4 << 2));
    float wk = w8[k];
    acc += v * wk;
  }
  half4_t o;
  o[0] = (_Float16)acc[0]; o[1] = (_Float16)acc[1];
  o[2] = (_Float16)acc[2]; o[3] = (_Float16)acc[3];
  *(half4_t*)(outp + ((size_t)r << 9) + (d4 << 2)) = o;
}

// ---------------------------------------------------------------------------
// y = LayerNorm(xa + xb) * g + be   (one wave per 512-wide row)
// ---------------------------------------------------------------------------
__global__ __launch_bounds__(256) void ln_add(
    const float* __restrict__ xa, const float* __restrict__ xb,
    const float* __restrict__ g, const float* __restrict__ be,
    float* __restrict__ y)
{
  const int lane = threadIdx.x & 63;
  const int row  = (blockIdx.x << 2) + (threadIdx.x >> 6);
  const size_t base = (size_t)row << 9;
  const float* ar = xa + base + (lane << 3);
  const float* br = xb + base + (lane << 3);
  f32x4_t a0 = *(const f32x4_t*)ar,       a1 = *(const f32x4_t*)(ar + 4);
  f32x4_t b0 = *(const f32x4_t*)br,       b1 = *(const f32x4_t*)(br + 4);
  f32x4_t v0 = a0 + b0, v1 = a1 + b1;
  float s  = v0[0] + v0[1] + v0[2] + v0[3] + v1[0] + v1[1] + v1[2] + v1[3];
  float s2 = v0[0]*v0[0] + v0[1]*v0[1] + v0[2]*v0[2] + v0[3]*v0[3]
           + v1[0]*v1[0] + v1[1]*v1[1] + v1[2]*v1[2] + v1[3]*v1[3];
  #pragma unroll
  for (int o = 1; o < 64; o <<= 1) { s += __shfl_xor(s, o); s2 += __shfl_xor(s2, o); }
  float mu  = s * (1.f / 512.f);
  float var = s2 * (1.f / 512.f) - mu * mu;
  float rs  = rsqrtf(var + 1e-5f);
  const float* gr  = g  + (lane << 3);
  const float* ber = be + (lane << 3);
  f32x4_t g0 = *(const f32x4_t*)gr,  g1v = *(const f32x4_t*)(gr + 4);
  f32x4_t e0 = *(const f32x4_t*)ber, e1  = *(const f32x4_t*)(ber + 4);
  f32x4_t o0, o1;
  #pragma unroll
  for (int i = 0; i < 4; ++i) {
    o0[i] = (v0[i] - mu) * rs * g0[i]  + e0[i];
    o1[i] = (v1[i] - mu) * rs * g1v[i] + e1[i];
  }
  float* yr = y + base + (lane << 3);
  *(f32x4_t*)yr = o0; *(f32x4_t*)(yr + 4) = o1;
}

// ---------------------------------------------------------------------------
// Series decomposition: moving average window 25, edge-replicated.
// mode 1: write seasonal fp32 + fp16, trend fp32
// mode 2: write seasonal fp32 (d_out), trendOut += trend (trend1+trend2)
// ---------------------------------------------------------------------------
__global__ __launch_bounds__(256) void movavg_decomp(
    const float* __restrict__ y, float* __restrict__ seasF,
    _Float16* __restrict__ seasH, float* __restrict__ trendOut, int mode)
{
  __shared__ float T[152 * 64];
  const int lt = blockIdx.x, dc = blockIdx.y, b = blockIdx.z;
  const int l0 = lt << 7, d0 = dc << 6;
  const int tid = threadIdx.x;
  for (int idx = tid; idx < 152 * 16; idx += 256) {
    int rr = idx >> 4, c4 = idx & 15;
    int ls = l0 - 12 + rr;
    ls = ls < 0 ? 0 : (ls > 4095 ? 4095 : ls);
    *(f32x4_t*)&T[rr * 64 + (c4 << 2)] =
        *(const f32x4_t*)(y + (((size_t)(b << 12) + ls) << 9) + d0 + (c4 << 2));
  }
  __syncthreads();
  for (int idx = tid; idx < 128 * 16; idx += 256) {
    int rr = idx >> 4, c4 = idx & 15;
    f32x4_t s = (f32x4_t){0.f, 0.f, 0.f, 0.f};
    #pragma unroll
    for (int j = 0; j < 25; ++j) s += *(const f32x4_t*)&T[(rr + j) * 64 + (c4 << 2)];
    f32x4_t trend = s * (1.f / 25.f);
    f32x4_t ctr   = *(const f32x4_t*)&T[(rr + 12) * 64 + (c4 << 2)];
    f32x4_t seas  = ctr - trend;
    size_t gp = (((size_t)(b << 12) + l0 + rr) << 9) + d0 + (c4 << 2);
    if (mode == 1) {
      *(f32x4_t*)(seasF + gp) = seas;
      half4_t sh;
      sh[0] = (_Float16)seas[0]; sh[1] = (_Float16)seas[1];
      sh[2] = (_Float16)seas[2]; sh[3] = (_Float16)seas[3];
      *(half4_t*)(seasH + gp) = sh;
      *(f32x4_t*)(trendOut + gp) = trend;
    } else {
      *(f32x4_t*)(seasF + gp) = seas;
      f32x4_t t1 = *(const f32x4_t*)(trendOut + gp);
      t1 += trend;
      *(f32x4_t*)(trendOut + gp) = t1;
    }
  }
}

// ---------------------------------------------------------------------------
// Weight prep: dst[n,k] = (fp16) src[k,n]
// ---------------------------------------------------------------------------
__global__ __launch_bounds__(256) void transpose_w(
    const float* __restrict__ src, _Float16* __restrict__ dst, int Kd, int Nd)
{
  __shared__ float t[32][33];
  const int kb = blockIdx.x << 5, nb = blockIdx.y << 5;
  const int tx = threadIdx.x & 31, ty = threadIdx.x >> 5;
  #pragma unroll
  for (int r0 = 0; r0 < 32; r0 += 8)
    t[ty + r0][tx] = src[(size_t)(kb + ty + r0) * Nd + nb + tx];
  __syncthreads();
  #pragma unroll
  for (int r0 = 0; r0 < 32; r0 += 8)
    dst[(size_t)(nb + ty + r0) * Kd + kb + tx] = (_Float16)t[tx][ty + r0];
}

__global__ __launch_bounds__(256) void f32_to_f16v(
    const float* __restrict__ src, _Float16* __restrict__ dst, int n4)
{
  int i = blockIdx.x * 256 + threadIdx.x;
  if (i >= n4) return;
  f32x4_t v = *(const f32x4_t*)(src + ((size_t)i << 2));
  half4_t o;
  o[0] = (_Float16)v[0]; o[1] = (_Float16)v[1];
  o[2] = (_Float16)v[2]; o[3] = (_Float16)v[3];
  *(half4_t*)(dst + ((size_t)i << 2)) = o;
}

// ---------------------------------------------------------------------------
extern "C" void kernel_launch(void* const* d_in, const int* in_sizes, int n_in,
                              void* d_out, int out_size, void* d_ws, size_t ws_size,
                              hipStream_t stream)
{
  const float* x   = (const float*)d_in[0];
  const float* Wq  = (const float*)d_in[1];
  const float* bq  = (const float*)d_in[2];
  const float* Wk  = (const float*)d_in[3];
  const float* bk  = (const float*)d_in[4];
  const float* Wv  = (const float*)d_in[5];
  const float* bv  = (const float*)d_in[6];
  const float* Wo  = (const float*)d_in[7];
  const float* bo  = (const float*)d_in[8];
  const float* W1  = (const float*)d_in[9];
  const float* b1  = (const float*)d_in[10];
  const float* W2  = (const float*)d_in[11];
  const float* b2  = (const float*)d_in[12];
  const float* g1  = (const float*)d_in[13];
  const float* be1 = (const float*)d_in[14];
  const float* g2  = (const float*)d_in[15];
  const float* be2 = (const float*)d_in[16];

  char* ws = (char*)d_ws;
  constexpr size_t ME = 16384ull * 512ull;                 // 8,388,608 elems
  constexpr size_t OFF_X16  = 0;                           // 16.8 MB fp16
  constexpr size_t OFF_WQT  = OFF_X16 + 2 * ME;
  constexpr size_t OFF_WKT  = OFF_WQT + 512 * 512 * 2;
  constexpr size_t OFF_WVT  = OFF_WKT + 512 * 512 * 2;
  constexpr size_t OFF_WOT  = OFF_WVT + 512 * 512 * 2;
  constexpr size_t OFF_W1T  = OFF_WOT + 512 * 512 * 2;
  constexpr size_t OFF_W2T  = OFF_W1T + 2048 * 512 * 2;
  constexpr size_t OFF_Q16  = OFF_W2T + 2048 * 512 * 2;
  constexpr size_t OFF_K16  = OFF_Q16 + 2 * ME;
  constexpr size_t OFF_V32  = OFF_K16 + 2 * ME;
  constexpr size_t OFF_CORR = OFF_V32 + 4 * ME;            // 32*4096 fp32
  constexpr size_t OFF_TW   = OFF_CORR + 32 * 4096 * 4;
  constexpr size_t OFF_TI   = OFF_TW + 1024;
  constexpr size_t OFF_ATTN = OFF_TI + 1024;
  constexpr size_t OFF_H16  = OFF_ATTN + 4 * ME;
  // aliases (lifetime-disjoint reuse)
  constexpr size_t OFF_AIN16 = OFF_X16;   // attn gather out (x16 dead)
  constexpr size_t OFF_S116  = OFF_X16;   // seasonal1 fp16 (attn-in dead)
  constexpr size_t OFF_S132  = OFF_Q16;   // seasonal1 fp32 spans Q16+K16
  constexpr size_t OFF_Y1    = OFF_V32;   // V dead after gather
  constexpr size_t OFF_Y2    = OFF_V32;   // y1 dead after movavg1
  constexpr size_t OFF_FF    = OFF_ATTN;  // attn dead after ln1

  _Float16* X16 = (_Float16*)(ws + OFF_X16);
  _Float16* WQT = (_Float16*)(ws + OFF_WQT);
  _Float16* WKT = (_Float16*)(ws + OFF_WKT);
  _Float16* WVT = (_Float16*)(ws + OFF_WVT);
  _Float16* WOT = (_Float16*)(ws + OFF_WOT);
  _Float16* W1T = (_Float16*)(ws + OFF_W1T);
  _Float16* W2T = (_Float16*)(ws + OFF_W2T);
  _Float16* Q16 = (_Float16*)(ws + OFF_Q16);
  _Float16* K16 = (_Float16*)(ws + OFF_K16);
  float*    V32 = (float*)(ws + OFF_V32);
  float*    CORR= (float*)(ws + OFF_CORR);
  float*    TW  = (float*)(ws + OFF_TW);
  int*      TI  = (int*)(ws + OFF_TI);
  float*    ATTN= (float*)(ws + OFF_ATTN);
  _Float16* H16 = (_Float16*)(ws + OFF_H16);
  _Float16* AIN16 = (_Float16*)(ws + OFF_AIN16);
  _Float16* S116  = (_Float16*)(ws + OFF_S116);
  float*    S132  = (float*)(ws + OFF_S132);
  float*    Y1    = (float*)(ws + OFF_Y1);
  float*    Y2    = (float*)(ws + OFF_Y2);
  float*    FF    = (float*)(ws + OFF_FF);

  float* OUT_SEAS  = (float*)d_out;            // seasonal2
  float* OUT_TREND = (float*)d_out + ME;       // trend1 + trend2

  // --- prep ---
  hipMemsetAsync(ws + OFF_CORR, 0, 32 * 4096 * 4, stream);
  f32_to_f16v<<<8192, 256, 0, stream>>>(x, X16, (int)(ME / 4));
  transpose_w<<<dim3(16, 16), 256, 0, stream>>>(Wq, WQT, 512, 512);
  transpose_w<<<dim3(16, 16), 256, 0, stream>>>(Wk, WKT, 512, 512);
  transpose_w<<<dim3(16, 16), 256, 0, stream>>>(Wv, WVT, 512, 512);
  transpose_w<<<dim3(16, 16), 256, 0, stream>>>(Wo, WOT, 512, 512);
  transpose_w<<<dim3(16, 64), 256, 0, stream>>>(W1, W1T, 512, 2048);
  transpose_w<<<dim3(64, 16), 256, 0, stream>>>(W2, W2T, 2048, 512);

  // --- projections ---
  gemm_f16k<true,  false><<<dim3(128, 4), 256, 0, stream>>>(X16, WQT, bq, Q16, 16384, 512, 512);
  gemm_f16k<true,  false><<<dim3(128, 4), 256, 0, stream>>>(X16, WKT, bk, K16, 16384, 512, 512);
  gemm_f16k<false, false><<<dim3(128, 4), 256, 0, stream>>>(X16, WVT, bv, V32, 16384, 512, 512);

  // --- autocorrelation ---
  corr_gram<<<dim3(64, 8, 4), 256, 0, stream>>>(Q16, K16, CORR);
  topk_softmax<<<32, 256, 0, stream>>>(CORR, TW, TI);
  gather_attn<<<8192, 256, 0, stream>>>(V32, TW, TI, AIN16);
  gemm_f16k<false, false><<<dim3(128, 4), 256, 0, stream>>>(AIN16, WOT, bo, ATTN, 16384, 512, 512);

  // --- LN1 + decomp1 ---
  ln_add<<<4096, 256, 0, stream>>>(x, ATTN, g1, be1, Y1);
  movavg_decomp<<<dim3(32, 8, 4), 256, 0, stream>>>(Y1, S132, S116, OUT_TREND, 1);

  // --- FFN ---
  gemm_f16k<true,  true ><<<dim3(128, 16), 256, 0, stream>>>(S116, W1T, b1, H16, 16384, 2048, 512);
  gemm_f16k<false, false><<<dim3(128, 4),  256, 0, stream>>>(H16, W2T, b2, FF, 16384, 512, 2048);

  // --- LN2 + decomp2 ---
  ln_add<<<4096, 256, 0, stream>>>(S132, FF, g2, be2, Y2);
  movavg_decomp<<<dim3(32, 8, 4), 256, 0, stream>>>(Y2, OUT_SEAS, (_Float16*)nullptr, OUT_TREND, 2);
}

// Round 2
// 729.394 us; speedup vs baseline: 1.4998x; 1.4998x over previous
//
#include <hip/hip_runtime.h>
#include <hip/hip_bf16.h>
#include <math.h>

// ---------------------------------------------------------------------------
// Autoformer encoder layer, MI355X (gfx950).
// B=4, L=4096, D=512, H=8, dk=64, F=2048, MA=25, top_k=8.
// All GEMMs in fp16 MFMA (16x16x32_f16), fp32 accumulate.
// ---------------------------------------------------------------------------

typedef _Float16 half8_t __attribute__((ext_vector_type(8)));
typedef _Float16 half4_t __attribute__((ext_vector_type(4)));
typedef float    f32x4_t __attribute__((ext_vector_type(4)));

__device__ __forceinline__ void gl_lds16(const _Float16* src, _Float16* dst) {
  __builtin_amdgcn_global_load_lds(
      (const __attribute__((address_space(1))) unsigned int*)(const void*)src,
      (__attribute__((address_space(3))) unsigned int*)(void*)dst, 16, 0, 0);
}

// ---------------------------------------------------------------------------
// Generic fp16 GEMM:  out[M,N] = A[M,K] @ Bt[N,K]^T + bias, optional GELU.
// 128x128 tile, BK=64, 256 threads (4 waves, 2x2), XOR-swizzled LDS.
// ---------------------------------------------------------------------------
template<bool OUT16, bool DOGELU>
__global__ __launch_bounds__(256) void gemm_f16k(
    const _Float16* __restrict__ A, const _Float16* __restrict__ Bt,
    const float* __restrict__ bias, void* __restrict__ outp,
    int M, int N, int K)
{
  __shared__ _Float16 As[128 * 64];
  __shared__ _Float16 Bs[128 * 64];
  const int tid = threadIdx.x, lane = tid & 63, w = tid >> 6;
  const int wr = w >> 1, wc = w & 1;
  const int m0 = blockIdx.x * 128, n0 = blockIdx.y * 128;

  f32x4_t acc[4][4];
  #pragma unroll
  for (int i = 0; i < 4; ++i)
    #pragma unroll
    for (int j = 0; j < 4; ++j) acc[i][j] = (f32x4_t){0.f, 0.f, 0.f, 0.f};

  const _Float16* Ab = A + (size_t)m0 * K;
  const _Float16* Bb = Bt + (size_t)n0 * K;

  for (int k0 = 0; k0 < K; k0 += 64) {
    #pragma unroll
    for (int q = 0; q < 4; ++q) {
      int off = ((w << 2) + q) << 10;            // byte offset of wave-issue
      int row = (off >> 7) + (lane >> 3);
      int sl  = (lane & 7) ^ (row & 7);          // logical k-slot for this phys slot
      gl_lds16(Ab + (size_t)row * K + k0 + (sl << 3), As + (off >> 1));
    }
    #pragma unroll
    for (int q = 0; q < 4; ++q) {
      int off = ((w << 2) + q) << 10;
      int row = (off >> 7) + (lane >> 3);
      int sl  = (lane & 7) ^ (row & 7);
      gl_lds16(Bb + (size_t)row * K + k0 + (sl << 3), Bs + (off >> 1));
    }
    __syncthreads();

    #pragma unroll
    for (int kk = 0; kk < 2; ++kk) {
      half8_t af[4], bf[4];
      #pragma unroll
      for (int mi = 0; mi < 4; ++mi) {
        int row = wr * 64 + mi * 16 + (lane & 15);
        int sl  = ((kk << 2) + (lane >> 4)) ^ (row & 7);
        af[mi] = *(const half8_t*)(As + row * 64 + (sl << 3));
      }
      #pragma unroll
      for (int ni = 0; ni < 4; ++ni) {
        int row = wc * 64 + ni * 16 + (lane & 15);
        int sl  = ((kk << 2) + (lane >> 4)) ^ (row & 7);
        bf[ni] = *(const half8_t*)(Bs + row * 64 + (sl << 3));
      }
      #pragma unroll
      for (int mi = 0; mi < 4; ++mi)
        #pragma unroll
        for (int ni = 0; ni < 4; ++ni)
          acc[mi][ni] = __builtin_amdgcn_mfma_f32_16x16x32_f16(
              af[mi], bf[ni], acc[mi][ni], 0, 0, 0);
    }
    __syncthreads();
  }

  float bvv[4];
  #pragma unroll
  for (int ni = 0; ni < 4; ++ni)
    bvv[ni] = bias[n0 + wc * 64 + ni * 16 + (lane & 15)];

  #pragma unroll
  for (int mi = 0; mi < 4; ++mi) {
    int rbase = m0 + wr * 64 + mi * 16 + ((lane >> 4) << 2);
    #pragma unroll
    for (int ni = 0; ni < 4; ++ni) {
      int col = n0 + wc * 64 + ni * 16 + (lane & 15);
      #pragma unroll
      for (int r = 0; r < 4; ++r) {
        float v = acc[mi][ni][r] + bvv[ni];
        if (DOGELU) v = 0.5f * v * (1.f + erff(v * 0.70710678118654752f));
        size_t idx = (size_t)(rbase + r) * N + col;
        if (OUT16) ((_Float16*)outp)[idx] = (_Float16)v;
        else       ((float*)outp)[idx]    = v;
      }
    }
  }
}

// ---------------------------------------------------------------------------
// Autocorrelation v2: block owns (b, h, tau-window [64T, 64T+64)).
// Per J: stacked 128x64 Gram tile M[i'][j] = Q[64(T+J)+i'] . K[64J+j];
// element M[j+v][j] contributes to tau = 64T+v exactly. MFMA output is
// scattered diagonal-major into Gd[v][j] (pad 68, 2-way max banks),
// thread v accumulates its 16-j slice into a register across all J.
// No atomics anywhere; one coalesced store per block at the end.
// ---------------------------------------------------------------------------
__global__ __launch_bounds__(256) void corr_gram2(
    const _Float16* __restrict__ Q, const _Float16* __restrict__ Kt,
    float* __restrict__ corr)
{
  __shared__ _Float16 Qs[2][64 * 64];
  __shared__ _Float16 Ks[64 * 64];
  __shared__ float __attribute__((aligned(16))) Gd[64 * 68];
  __shared__ float red[256];
  const int tid = threadIdx.x, lane = tid & 63, w = tid >> 6;
  const int T = blockIdx.x, h = blockIdx.y, b = blockIdx.z;

  // prologue: Q tiles T, T+1 (mod 64) and K tile 0
  {
    #pragma unroll
    for (int p = 0; p < 2; ++p) {
      int ti = (T + p) & 63;
      const size_t base = ((size_t)b * 4096 + ti * 64) * 512 + h * 64;
      _Float16* dst = Qs[ti & 1];
      #pragma unroll
      for (int q = 0; q < 2; ++q) {
        int off = ((w << 1) + q) << 10;
        int row = (off >> 7) + (lane >> 3);
        int sl  = (lane & 7) ^ (row & 7);
        gl_lds16(Q + base + (size_t)row * 512 + (sl << 3), dst + (off >> 1));
      }
    }
    const size_t baseK = ((size_t)b * 4096) * 512 + h * 64;
    #pragma unroll
    for (int q = 0; q < 2; ++q) {
      int off = ((w << 1) + q) << 10;
      int row = (off >> 7) + (lane >> 3);
      int sl  = (lane & 7) ^ (row & 7);
      gl_lds16(Kt + baseK + (size_t)row * 512 + (sl << 3), Ks + (off >> 1));
    }
  }
  float acc = 0.f;
  __syncthreads();

  for (int J = 0; J < 64; ++J) {
    // ---- fragments: wave w computes stacked rows [32w, 32w+32) x all 64 cols
    half8_t af[2][2], bf[4][2];
    #pragma unroll
    for (int mi = 0; mi < 2; ++mi) {
      int gr = (w << 5) + (mi << 4) + (lane & 15);   // stacked row 0..127
      int bi = (T + J + (gr >> 6)) & 1;
      int r  = gr & 63;
      #pragma unroll
      for (int kk = 0; kk < 2; ++kk) {
        int sl = ((kk << 2) + (lane >> 4)) ^ (r & 7);
        af[mi][kk] = *(const half8_t*)(&Qs[bi][r * 64 + (sl << 3)]);
      }
    }
    #pragma unroll
    for (int ni = 0; ni < 4; ++ni) {
      int r = (ni << 4) + (lane & 15);
      #pragma unroll
      for (int kk = 0; kk < 2; ++kk) {
        int sl = ((kk << 2) + (lane >> 4)) ^ (r & 7);
        bf[ni][kk] = *(const half8_t*)(&Ks[r * 64 + (sl << 3)]);
      }
    }
    f32x4_t g[2][4];
    #pragma unroll
    for (int mi = 0; mi < 2; ++mi)
      #pragma unroll
      for (int ni = 0; ni < 4; ++ni) {
        f32x4_t a = (f32x4_t){0.f, 0.f, 0.f, 0.f};
        a = __builtin_amdgcn_mfma_f32_16x16x32_f16(af[mi][0], bf[ni][0], a, 0, 0, 0);
        a = __builtin_amdgcn_mfma_f32_16x16x32_f16(af[mi][1], bf[ni][1], a, 0, 0, 0);
        g[mi][ni] = a;
      }

    // ---- scatter to diagonal-major Gd[v][j] (predicated to v in [0,64))
    #pragma unroll
    for (int mi = 0; mi < 2; ++mi)
      #pragma unroll
      for (int ni = 0; ni < 4; ++ni)
        #pragma unroll
        for (int r = 0; r < 4; ++r) {
          int i2 = (w << 5) + (mi << 4) + ((lane >> 4) << 2) + r;
          int j2 = (ni << 4) + (lane & 15);
          int v  = i2 - j2;
          if (v >= 0 && v < 64) Gd[v * 68 + j2] = g[mi][ni][r];
        }
    __syncthreads();

    // ---- prefetch next tiles (overlaps diagonal phase)
    if (J < 63) {
      int tiK = J + 1;
      const size_t baseK = ((size_t)b * 4096 + tiK * 64) * 512 + h * 64;
      #pragma unroll
      for (int q = 0; q < 2; ++q) {
        int off = ((w << 1) + q) << 10;
        int row = (off >> 7) + (lane >> 3);
        int sl  = (lane & 7) ^ (row & 7);
        gl_lds16(Kt + baseK + (size_t)row * 512 + (sl << 3), Ks + (off >> 1));
      }
      int tiQ = (T + J + 2) & 63;
      const size_t baseQ = ((size_t)b * 4096 + tiQ * 64) * 512 + h * 64;
      _Float16* dst = Qs[tiQ & 1];
      #pragma unroll
      for (int q = 0; q < 2; ++q) {
        int off = ((w << 1) + q) << 10;
        int row = (off >> 7) + (lane >> 3);
        int sl  = (lane & 7) ^ (row & 7);
        gl_lds16(Q + baseQ + (size_t)row * 512 + (sl << 3), dst + (off >> 1));
      }
    }

    // ---- diagonal accumulate: thread (w,lane): v=lane, j in [16w,16w+16)
    {
      const float* gp = &Gd[lane * 68 + (w << 4)];
      f32x4_t x0 = *(const f32x4_t*)gp;
      f32x4_t x1 = *(const f32x4_t*)(gp + 4);
      f32x4_t x2 = *(const f32x4_t*)(gp + 8);
      f32x4_t x3 = *(const f32x4_t*)(gp + 12);
      x0 += x1; x2 += x3; x0 += x2;
      acc += x0[0] + x0[1] + x0[2] + x0[3];
    }
    __syncthreads();   // Gd free for next J; staged tiles landed (vmcnt drain)
  }

  red[tid] = acc;
  __syncthreads();
  if (w == 0) {
    float s = red[lane] + red[64 + lane] + red[128 + lane] + red[192 + lane];
    corr[(((size_t)(b * 8 + h)) << 12) + (T << 6) + lane] = s;
  }
}

// ---------------------------------------------------------------------------
// Top-8 + softmax per (b,h). Tie-break: lowest index (matches stable top_k).
// ---------------------------------------------------------------------------
__global__ __launch_bounds__(256) void topk_softmax(
    const float* __restrict__ corr, float* __restrict__ tw, int* __restrict__ ti)
{
  __shared__ float vals[4096];
  __shared__ float wvv[4]; __shared__ int wii[4];
  __shared__ float rv[8]; __shared__ int ri[8];
  const int tid = threadIdx.x;
  const int bh = blockIdx.x;
  const float* c = corr + (size_t)bh * 4096;
  for (int i = tid; i < 4096; i += 256) vals[i] = c[i];
  __syncthreads();

  for (int it = 0; it < 8; ++it) {
    float bv = -3.4e38f; int bi = 1 << 30;
    for (int i = tid; i < 4096; i += 256) {
      float v = vals[i];
      if (v > bv) { bv = v; bi = i; }
    }
    #pragma unroll
    for (int o = 32; o > 0; o >>= 1) {
      float ov = __shfl_down(bv, o);
      int   oi = __shfl_down(bi, o);
      if (ov > bv || (ov == bv && oi < bi)) { bv = ov; bi = oi; }
    }
    if ((tid & 63) == 0) { wvv[tid >> 6] = bv; wii[tid >> 6] = bi; }
    __syncthreads();
    if (tid == 0) {
      for (int k = 1; k < 4; ++k)
        if (wvv[k] > bv || (wvv[k] == bv && wii[k] < bi)) { bv = wvv[k]; bi = wii[k]; }
      rv[it] = bv; ri[it] = bi; vals[bi] = -3.4e38f;
    }
    __syncthreads();
  }

  if (tid == 0) {
    float m = rv[0] * (1.f / 64.f);          // corr_mean = corr/dk; rv[0] is max
    float e[8]; float s = 0.f;
    for (int k = 0; k < 8; ++k) { e[k] = expf(rv[k] * (1.f / 64.f) - m); s += e[k]; }
    float inv = 1.f / s;
    for (int k = 0; k < 8; ++k) { tw[bh * 8 + k] = e[k] * inv; ti[bh * 8 + k] = ri[k]; }
  }
}

// ---------------------------------------------------------------------------
// out[b,l,h*64+d] = sum_k tw[k] * V[b,(l+ti[k])%L, h*64+d], stored fp16.
// ---------------------------------------------------------------------------
__global__ __launch_bounds__(256) void gather_attn(
    const float* __restrict__ V, const float* __restrict__ tw,
    const int* __restrict__ ti, _Float16* __restrict__ outp)
{
  const int tid = threadIdx.x;
  const int d4 = tid & 127;
  const int r  = (blockIdx.x << 1) + (tid >> 7);
  const int b  = r >> 12, l = r & 4095;
  const int h  = d4 >> 4;
  const float* w8 = tw + (((b << 3) + h) << 3);
  const int*   i8 = ti + (((b << 3) + h) << 3);
  f32x4_t acc = (f32x4_t){0.f, 0.f, 0.f, 0.f};
  #pragma unroll
  for (int k = 0; k < 8; ++k) {
    int ls = (l + i8[k]) & 4095;
    f32x4_t v = *(const f32x4_t*)(V + (((size_t)(b << 12) + ls) << 9) + (d4 << 2));
    float wk = w8[k];
    acc += v * wk;
  }
  half4_t o;
  o[0] = (_Float16)acc[0]; o[1] = (_Float16)acc[1];
  o[2] = (_Float16)acc[2]; o[3] = (_Float16)acc[3];
  *(half4_t*)(outp + ((size_t)r << 9) + (d4 << 2)) = o;
}

// ---------------------------------------------------------------------------
// y = LayerNorm(xa + xb) * g + be   (one wave per 512-wide row)
// ---------------------------------------------------------------------------
__global__ __launch_bounds__(256) void ln_add(
    const float* __restrict__ xa, const float* __restrict__ xb,
    const float* __restrict__ g, const float* __restrict__ be,
    float* __restrict__ y)
{
  const int lane = threadIdx.x & 63;
  const int row  = (blockIdx.x << 2) + (threadIdx.x >> 6);
  const size_t base = (size_t)row << 9;
  const float* ar = xa + base + (lane << 3);
  const float* br = xb + base + (lane << 3);
  f32x4_t a0 = *(const f32x4_t*)ar,       a1 = *(const f32x4_t*)(ar + 4);
  f32x4_t b0 = *(const f32x4_t*)br,       b1 = *(const f32x4_t*)(br + 4);
  f32x4_t v0 = a0 + b0, v1 = a1 + b1;
  float s  = v0[0] + v0[1] + v0[2] + v0[3] + v1[0] + v1[1] + v1[2] + v1[3];
  float s2 = v0[0]*v0[0] + v0[1]*v0[1] + v0[2]*v0[2] + v0[3]*v0[3]
           + v1[0]*v1[0] + v1[1]*v1[1] + v1[2]*v1[2] + v1[3]*v1[3];
  #pragma unroll
  for (int o = 1; o < 64; o <<= 1) { s += __shfl_xor(s, o); s2 += __shfl_xor(s2, o); }
  float mu  = s * (1.f / 512.f);
  float var = s2 * (1.f / 512.f) - mu * mu;
  float rs  = rsqrtf(var + 1e-5f);
  const float* gr  = g  + (lane << 3);
  const float* ber = be + (lane << 3);
  f32x4_t g0 = *(const f32x4_t*)gr,  g1v = *(const f32x4_t*)(gr + 4);
  f32x4_t e0 = *(const f32x4_t*)ber, e1  = *(const f32x4_t*)(ber + 4);
  f32x4_t o0, o1;
  #pragma unroll
  for (int i = 0; i < 4; ++i) {
    o0[i] = (v0[i] - mu) * rs * g0[i]  + e0[i];
    o1[i] = (v1[i] - mu) * rs * g1v[i] + e1[i];
  }
  float* yr = y + base + (lane << 3);
  *(f32x4_t*)yr = o0; *(f32x4_t*)(yr + 4) = o1;
}

// ---------------------------------------------------------------------------
// Series decomposition: moving average window 25, edge-replicated.
// mode 1: write seasonal fp32 + fp16, trend fp32
// mode 2: write seasonal fp32 (d_out), trendOut += trend (trend1+trend2)
// ---------------------------------------------------------------------------
__global__ __launch_bounds__(256) void movavg_decomp(
    const float* __restrict__ y, float* __restrict__ seasF,
    _Float16* __restrict__ seasH, float* __restrict__ trendOut, int mode)
{
  __shared__ float T[152 * 64];
  const int lt = blockIdx.x, dc = blockIdx.y, b = blockIdx.z;
  const int l0 = lt << 7, d0 = dc << 6;
  const int tid = threadIdx.x;
  for (int idx = tid; idx < 152 * 16; idx += 256) {
    int rr = idx >> 4, c4 = idx & 15;
    int ls = l0 - 12 + rr;
    ls = ls < 0 ? 0 : (ls > 4095 ? 4095 : ls);
    *(f32x4_t*)&T[rr * 64 + (c4 << 2)] =
        *(const f32x4_t*)(y + (((size_t)(b << 12) + ls) << 9) + d0 + (c4 << 2));
  }
  __syncthreads();
  for (int idx = tid; idx < 128 * 16; idx += 256) {
    int rr = idx >> 4, c4 = idx & 15;
    f32x4_t s = (f32x4_t){0.f, 0.f, 0.f, 0.f};
    #pragma unroll
    for (int j = 0; j < 25; ++j) s += *(const f32x4_t*)&T[(rr + j) * 64 + (c4 << 2)];
    f32x4_t trend = s * (1.f / 25.f);
    f32x4_t ctr   = *(const f32x4_t*)&T[(rr + 12) * 64 + (c4 << 2)];
    f32x4_t seas  = ctr - trend;
    size_t gp = (((size_t)(b << 12) + l0 + rr) << 9) + d0 + (c4 << 2);
    if (mode == 1) {
      *(f32x4_t*)(seasF + gp) = seas;
      half4_t sh;
      sh[0] = (_Float16)seas[0]; sh[1] = (_Float16)seas[1];
      sh[2] = (_Float16)seas[2]; sh[3] = (_Float16)seas[3];
      *(half4_t*)(seasH + gp) = sh;
      *(f32x4_t*)(trendOut + gp) = trend;
    } else {
      *(f32x4_t*)(seasF + gp) = seas;
      f32x4_t t1 = *(const f32x4_t*)(trendOut + gp);
      t1 += trend;
      *(f32x4_t*)(trendOut + gp) = t1;
    }
  }
}

// ---------------------------------------------------------------------------
// Weight prep: dst[n,k] = (fp16) src[k,n]
// ---------------------------------------------------------------------------
__global__ __launch_bounds__(256) void transpose_w(
    const float* __restrict__ src, _Float16* __restrict__ dst, int Kd, int Nd)
{
  __shared__ float t[32][33];
  const int kb = blockIdx.x << 5, nb = blockIdx.y << 5;
  const int tx = threadIdx.x & 31, ty = threadIdx.x >> 5;
  #pragma unroll
  for (int r0 = 0; r0 < 32; r0 += 8)
    t[ty + r0][tx] = src[(size_t)(kb + ty + r0) * Nd + nb + tx];
  __syncthreads();
  #pragma unroll
  for (int r0 = 0; r0 < 32; r0 += 8)
    dst[(size_t)(nb + ty + r0) * Kd + kb + tx] = (_Float16)t[tx][ty + r0];
}

__global__ __launch_bounds__(256) void f32_to_f16v(
    const float* __restrict__ src, _Float16* __restrict__ dst, int n4)
{
  int i = blockIdx.x * 256 + threadIdx.x;
  if (i >= n4) return;
  f32x4_t v = *(const f32x4_t*)(src + ((size_t)i << 2));
  half4_t o;
  o[0] = (_Float16)v[0]; o[1] = (_Float16)v[1];
  o[2] = (_Float16)v[2]; o[3] = (_Float16)v[3];
  *(half4_t*)(dst + ((size_t)i << 2)) = o;
}

// ---------------------------------------------------------------------------
extern "C" void kernel_launch(void* const* d_in, const int* in_sizes, int n_in,
                              void* d_out, int out_size, void* d_ws, size_t ws_size,
                              hipStream_t stream)
{
  const float* x   = (const float*)d_in[0];
  const float* Wq  = (const float*)d_in[1];
  const float* bq  = (const float*)d_in[2];
  const float* Wk  = (const float*)d_in[3];
  const float* bk  = (const float*)d_in[4];
  const float* Wv  = (const float*)d_in[5];
  const float* bv  = (const float*)d_in[6];
  const float* Wo  = (const float*)d_in[7];
  const float* bo  = (const float*)d_in[8];
  const float* W1  = (const float*)d_in[9];
  const float* b1  = (const float*)d_in[10];
  const float* W2  = (const float*)d_in[11];
  const float* b2  = (const float*)d_in[12];
  const float* g1  = (const float*)d_in[13];
  const float* be1 = (const float*)d_in[14];
  const float* g2  = (const float*)d_in[15];
  const float* be2 = (const float*)d_in[16];

  char* ws = (char*)d_ws;
  constexpr size_t ME = 16384ull * 512ull;                 // 8,388,608 elems
  constexpr size_t OFF_X16  = 0;                           // 16.8 MB fp16
  constexpr size_t OFF_WQT  = OFF_X16 + 2 * ME;
  constexpr size_t OFF_WKT  = OFF_WQT + 512 * 512 * 2;
  constexpr size_t OFF_WVT  = OFF_WKT + 512 * 512 * 2;
  constexpr size_t OFF_WOT  = OFF_WVT + 512 * 512 * 2;
  constexpr size_t OFF_W1T  = OFF_WOT + 512 * 512 * 2;
  constexpr size_t OFF_W2T  = OFF_W1T + 2048 * 512 * 2;
  constexpr size_t OFF_Q16  = OFF_W2T + 2048 * 512 * 2;
  constexpr size_t OFF_K16  = OFF_Q16 + 2 * ME;
  constexpr size_t OFF_V32  = OFF_K16 + 2 * ME;
  constexpr size_t OFF_CORR = OFF_V32 + 4 * ME;            // 32*4096 fp32
  constexpr size_t OFF_TW   = OFF_CORR + 32 * 4096 * 4;
  constexpr size_t OFF_TI   = OFF_TW + 1024;
  constexpr size_t OFF_ATTN = OFF_TI + 1024;
  constexpr size_t OFF_H16  = OFF_ATTN + 4 * ME;
  // aliases (lifetime-disjoint reuse)
  constexpr size_t OFF_AIN16 = OFF_X16;   // attn gather out (x16 dead)
  constexpr size_t OFF_S116  = OFF_X16;   // seasonal1 fp16 (attn-in dead)
  constexpr size_t OFF_S132  = OFF_Q16;   // seasonal1 fp32 spans Q16+K16
  constexpr size_t OFF_Y1    = OFF_V32;   // V dead after gather
  constexpr size_t OFF_Y2    = OFF_V32;   // y1 dead after movavg1
  constexpr size_t OFF_FF    = OFF_ATTN;  // attn dead after ln1

  _Float16* X16 = (_Float16*)(ws + OFF_X16);
  _Float16* WQT = (_Float16*)(ws + OFF_WQT);
  _Float16* WKT = (_Float16*)(ws + OFF_WKT);
  _Float16* WVT = (_Float16*)(ws + OFF_WVT);
  _Float16* WOT = (_Float16*)(ws + OFF_WOT);
  _Float16* W1T = (_Float16*)(ws + OFF_W1T);
  _Float16* W2T = (_Float16*)(ws + OFF_W2T);
  _Float16* Q16 = (_Float16*)(ws + OFF_Q16);
  _Float16* K16 = (_Float16*)(ws + OFF_K16);
  float*    V32 = (float*)(ws + OFF_V32);
  float*    CORR= (float*)(ws + OFF_CORR);
  float*    TW  = (float*)(ws + OFF_TW);
  int*      TI  = (int*)(ws + OFF_TI);
  float*    ATTN= (float*)(ws + OFF_ATTN);
  _Float16* H16 = (_Float16*)(ws + OFF_H16);
  _Float16* AIN16 = (_Float16*)(ws + OFF_AIN16);
  _Float16* S116  = (_Float16*)(ws + OFF_S116);
  float*    S132  = (float*)(ws + OFF_S132);
  float*    Y1    = (float*)(ws + OFF_Y1);
  float*    Y2    = (float*)(ws + OFF_Y2);
  float*    FF    = (float*)(ws + OFF_FF);

  float* OUT_SEAS  = (float*)d_out;            // seasonal2
  float* OUT_TREND = (float*)d_out + ME;       // trend1 + trend2

  // --- prep ---
  f32_to_f16v<<<8192, 256, 0, stream>>>(x, X16, (int)(ME / 4));
  transpose_w<<<dim3(16, 16), 256, 0, stream>>>(Wq, WQT, 512, 512);
  transpose_w<<<dim3(16, 16), 256, 0, stream>>>(Wk, WKT, 512, 512);
  transpose_w<<<dim3(16, 16), 256, 0, stream>>>(Wv, WVT, 512, 512);
  transpose_w<<<dim3(16, 16), 256, 0, stream>>>(Wo, WOT, 512, 512);
  transpose_w<<<dim3(16, 64), 256, 0, stream>>>(W1, W1T, 512, 2048);
  transpose_w<<<dim3(64, 16), 256, 0, stream>>>(W2, W2T, 2048, 512);

  // --- projections ---
  gemm_f16k<true,  false><<<dim3(128, 4), 256, 0, stream>>>(X16, WQT, bq, Q16, 16384, 512, 512);
  gemm_f16k<true,  false><<<dim3(128, 4), 256, 0, stream>>>(X16, WKT, bk, K16, 16384, 512, 512);
  gemm_f16k<false, false><<<dim3(128, 4), 256, 0, stream>>>(X16, WVT, bv, V32, 16384, 512, 512);

  // --- autocorrelation ---
  corr_gram2<<<dim3(64, 8, 4), 256, 0, stream>>>(Q16, K16, CORR);
  topk_softmax<<<32, 256, 0, stream>>>(CORR, TW, TI);
  gather_attn<<<8192, 256, 0, stream>>>(V32, TW, TI, AIN16);
  gemm_f16k<false, false><<<dim3(128, 4), 256, 0, stream>>>(AIN16, WOT, bo, ATTN, 16384, 512, 512);

  // --- LN1 + decomp1 ---
  ln_add<<<4096, 256, 0, stream>>>(x, ATTN, g1, be1, Y1);
  movavg_decomp<<<dim3(32, 8, 4), 256, 0, stream>>>(Y1, S132, S116, OUT_TREND, 1);

  // --- FFN ---
  gemm_f16k<true,  true ><<<dim3(128, 16), 256, 0, stream>>>(S116, W1T, b1, H16, 16384, 2048, 512);
  gemm_f16k<false, false><<<dim3(128, 4),  256, 0, stream>>>(H16, W2T, b2, FF, 16384, 512, 2048);

  // --- LN2 + decomp2 ---
  ln_add<<<4096, 256, 0, stream>>>(S132, FF, g2, be2, Y2);
  movavg_decomp<<<dim3(32, 8, 4), 256, 0, stream>>>(Y2, OUT_SEAS, (_Float16*)nullptr, OUT_TREND, 2);
}

// Round 3
// 636.387 us; speedup vs baseline: 1.7190x; 1.1461x over previous
//
#include <hip/hip_runtime.h>
#include <hip/hip_bf16.h>
#include <math.h>

// ---------------------------------------------------------------------------
// Autoformer encoder layer, MI355X (gfx950).
// B=4, L=4096, D=512, H=8, dk=64, F=2048, MA=25, top_k=8.
// All GEMMs in fp16 MFMA (16x16x32_f16), fp32 accumulate.
// ---------------------------------------------------------------------------

typedef _Float16 half8_t __attribute__((ext_vector_type(8)));
typedef _Float16 half4_t __attribute__((ext_vector_type(4)));
typedef float    f32x4_t __attribute__((ext_vector_type(4)));

__device__ __forceinline__ void gl_lds16(const _Float16* src, _Float16* dst) {
  __builtin_amdgcn_global_load_lds(
      (const __attribute__((address_space(1))) unsigned int*)(const void*)src,
      (__attribute__((address_space(3))) unsigned int*)(void*)dst, 16, 0, 0);
}

// ---------------------------------------------------------------------------
// Generic fp16 GEMM:  out[M,N] = A[M,K] @ Bt[N,K]^T + bias, optional GELU.
// 128x128 tile, BK=64, 256 threads (4 waves, 2x2), XOR-swizzled LDS.
// ---------------------------------------------------------------------------
template<bool OUT16, bool DOGELU>
__global__ __launch_bounds__(256) void gemm_f16k(
    const _Float16* __restrict__ A, const _Float16* __restrict__ Bt,
    const float* __restrict__ bias, void* __restrict__ outp,
    int M, int N, int K)
{
  __shared__ _Float16 As[128 * 64];
  __shared__ _Float16 Bs[128 * 64];
  const int tid = threadIdx.x, lane = tid & 63, w = tid >> 6;
  const int wr = w >> 1, wc = w & 1;
  const int m0 = blockIdx.x * 128, n0 = blockIdx.y * 128;

  f32x4_t acc[4][4];
  #pragma unroll
  for (int i = 0; i < 4; ++i)
    #pragma unroll
    for (int j = 0; j < 4; ++j) acc[i][j] = (f32x4_t){0.f, 0.f, 0.f, 0.f};

  const _Float16* Ab = A + (size_t)m0 * K;
  const _Float16* Bb = Bt + (size_t)n0 * K;

  for (int k0 = 0; k0 < K; k0 += 64) {
    #pragma unroll
    for (int q = 0; q < 4; ++q) {
      int off = ((w << 2) + q) << 10;            // byte offset of wave-issue
      int row = (off >> 7) + (lane >> 3);
      int sl  = (lane & 7) ^ (row & 7);          // logical k-slot for this phys slot
      gl_lds16(Ab + (size_t)row * K + k0 + (sl << 3), As + (off >> 1));
    }
    #pragma unroll
    for (int q = 0; q < 4; ++q) {
      int off = ((w << 2) + q) << 10;
      int row = (off >> 7) + (lane >> 3);
      int sl  = (lane & 7) ^ (row & 7);
      gl_lds16(Bb + (size_t)row * K + k0 + (sl << 3), Bs + (off >> 1));
    }
    __syncthreads();

    #pragma unroll
    for (int kk = 0; kk < 2; ++kk) {
      half8_t af[4], bf[4];
      #pragma unroll
      for (int mi = 0; mi < 4; ++mi) {
        int row = wr * 64 + mi * 16 + (lane & 15);
        int sl  = ((kk << 2) + (lane >> 4)) ^ (row & 7);
        af[mi] = *(const half8_t*)(As + row * 64 + (sl << 3));
      }
      #pragma unroll
      for (int ni = 0; ni < 4; ++ni) {
        int row = wc * 64 + ni * 16 + (lane & 15);
        int sl  = ((kk << 2) + (lane >> 4)) ^ (row & 7);
        bf[ni] = *(const half8_t*)(Bs + row * 64 + (sl << 3));
      }
      #pragma unroll
      for (int mi = 0; mi < 4; ++mi)
        #pragma unroll
        for (int ni = 0; ni < 4; ++ni)
          acc[mi][ni] = __builtin_amdgcn_mfma_f32_16x16x32_f16(
              af[mi], bf[ni], acc[mi][ni], 0, 0, 0);
    }
    __syncthreads();
  }

  float bvv[4];
  #pragma unroll
  for (int ni = 0; ni < 4; ++ni)
    bvv[ni] = bias[n0 + wc * 64 + ni * 16 + (lane & 15)];

  #pragma unroll
  for (int mi = 0; mi < 4; ++mi) {
    int rbase = m0 + wr * 64 + mi * 16 + ((lane >> 4) << 2);
    #pragma unroll
    for (int ni = 0; ni < 4; ++ni) {
      int col = n0 + wc * 64 + ni * 16 + (lane & 15);
      #pragma unroll
      for (int r = 0; r < 4; ++r) {
        float v = acc[mi][ni][r] + bvv[ni];
        if (DOGELU) v = 0.5f * v * (1.f + erff(v * 0.70710678118654752f));
        size_t idx = (size_t)(rbase + r) * N + col;
        if (OUT16) ((_Float16*)outp)[idx] = (_Float16)v;
        else       ((float*)outp)[idx]    = v;
      }
    }
  }
}

// ---------------------------------------------------------------------------
// Autocorrelation v3: block owns (b, h, tau-window [64T, 64T+64)).
// Band tiles only: per J, ONE 64x64 tile M[i][j] = Q[64((T+J)&63)+i].K[64J+j].
// Scatter ALL entries diagonal-major: Gd[v][j], v = i-j+64 in [1,127].
// Positive diags (v>=64) -> corrP[64T + v-64]; negative (v<64) ->
// corrN[(64T + v-64) & 4095] (window T-1's tau, disjoint slots, no atomics).
// Gd zero-initialized once; ragged edges stay 0 -> blind 32-float reads.
// Final diag sums via shfl_xor pair reduce; one store per diagonal.
// XCD-chunked swizzle: all 64 T-blocks of one (b,h) land on one XCD.
// ---------------------------------------------------------------------------
__global__ __launch_bounds__(256) void corr_gram3(
    const _Float16* __restrict__ Q, const _Float16* __restrict__ Kt,
    float* __restrict__ corrP, float* __restrict__ corrN)
{
  __shared__ _Float16 Qs[64 * 64];
  __shared__ _Float16 Ks[64 * 64];
  __shared__ float __attribute__((aligned(16))) Gd[128 * 68];
  const int tid = threadIdx.x, lane = tid & 63, w = tid >> 6;
  // XCD-chunked logical block id: phys p -> xcd p&7 owns contiguous chunk
  const int p  = blockIdx.x;
  const int lg = ((p & 7) << 8) + (p >> 3);
  const int T = lg & 63, h = (lg >> 6) & 7, b = lg >> 9;

  // zero Gd (invalid diag slots stay 0 forever)
  for (int i = tid; i < 128 * 68; i += 256) Gd[i] = 0.f;

  // prologue: stage Q tile T, K tile 0
  {
    const size_t baseQ = ((size_t)b * 4096 + T * 64) * 512 + h * 64;
    #pragma unroll
    for (int q = 0; q < 2; ++q) {
      int off = ((w << 1) + q) << 10;
      int row = (off >> 7) + (lane >> 3);
      int sl  = (lane & 7) ^ (row & 7);
      gl_lds16(Q + baseQ + (size_t)row * 512 + (sl << 3), Qs + (off >> 1));
    }
    const size_t baseK = ((size_t)b * 4096) * 512 + h * 64;
    #pragma unroll
    for (int q = 0; q < 2; ++q) {
      int off = ((w << 1) + q) << 10;
      int row = (off >> 7) + (lane >> 3);
      int sl  = (lane & 7) ^ (row & 7);
      gl_lds16(Kt + baseK + (size_t)row * 512 + (sl << 3), Ks + (off >> 1));
    }
  }
  float acc = 0.f;
  __syncthreads();

  for (int J = 0; J < 64; ++J) {
    // ---- fragments: wave w owns tile rows [16w, 16w+16), all 64 cols
    half8_t af[2], bf[4][2];
    {
      int row = (w << 4) + (lane & 15);
      #pragma unroll
      for (int kk = 0; kk < 2; ++kk) {
        int sl = ((kk << 2) + (lane >> 4)) ^ (row & 7);
        af[kk] = *(const half8_t*)(&Qs[row * 64 + (sl << 3)]);
      }
    }
    #pragma unroll
    for (int ni = 0; ni < 4; ++ni) {
      int row = (ni << 4) + (lane & 15);
      #pragma unroll
      for (int kk = 0; kk < 2; ++kk) {
        int sl = ((kk << 2) + (lane >> 4)) ^ (row & 7);
        bf[ni][kk] = *(const half8_t*)(&Ks[row * 64 + (sl << 3)]);
      }
    }
    f32x4_t g[4];
    #pragma unroll
    for (int ni = 0; ni < 4; ++ni) {
      f32x4_t a = (f32x4_t){0.f, 0.f, 0.f, 0.f};
      a = __builtin_amdgcn_mfma_f32_16x16x32_f16(af[0], bf[ni][0], a, 0, 0, 0);
      a = __builtin_amdgcn_mfma_f32_16x16x32_f16(af[1], bf[ni][1], a, 0, 0, 0);
      g[ni] = a;
    }

    // ---- scatter diagonal-major (2-way banks max = free)
    #pragma unroll
    for (int ni = 0; ni < 4; ++ni)
      #pragma unroll
      for (int r = 0; r < 4; ++r) {
        int iloc = (w << 4) + ((lane >> 4) << 2) + r;
        int jloc = (ni << 4) + (lane & 15);
        Gd[(iloc - jloc + 64) * 68 + jloc] = g[ni][r];
      }
    __syncthreads();

    // ---- prefetch next tiles (overlaps diagonal accumulate)
    if (J < 63) {
      const size_t baseK = ((size_t)b * 4096 + (J + 1) * 64) * 512 + h * 64;
      #pragma unroll
      for (int q = 0; q < 2; ++q) {
        int off = ((w << 1) + q) << 10;
        int row = (off >> 7) + (lane >> 3);
        int sl  = (lane & 7) ^ (row & 7);
        gl_lds16(Kt + baseK + (size_t)row * 512 + (sl << 3), Ks + (off >> 1));
      }
      int tiQ = (T + J + 1) & 63;
      const size_t baseQ = ((size_t)b * 4096 + tiQ * 64) * 512 + h * 64;
      #pragma unroll
      for (int q = 0; q < 2; ++q) {
        int off = ((w << 1) + q) << 10;
        int row = (off >> 7) + (lane >> 3);
        int sl  = (lane & 7) ^ (row & 7);
        gl_lds16(Q + baseQ + (size_t)row * 512 + (sl << 3), Qs + (off >> 1));
      }
    }

    // ---- diagonal accumulate: thread t reads 32 floats of diag v = t>>1
    {
      const float* gp = &Gd[(tid >> 1) * 68 + ((tid & 1) << 5)];
      f32x4_t x0 = *(const f32x4_t*)gp       + *(const f32x4_t*)(gp + 4);
      f32x4_t x1 = *(const f32x4_t*)(gp + 8) + *(const f32x4_t*)(gp + 12);
      f32x4_t x2 = *(const f32x4_t*)(gp + 16)+ *(const f32x4_t*)(gp + 20);
      f32x4_t x3 = *(const f32x4_t*)(gp + 24)+ *(const f32x4_t*)(gp + 28);
      x0 += x1; x2 += x3; x0 += x2;
      acc += x0[0] + x0[1] + x0[2] + x0[3];
    }
    __syncthreads();   // Gd free for next J; staged tiles landed (vmcnt drain)
  }

  // pair-reduce (t, t^1) hold the two halves of diag v = t>>1
  float o = __shfl_xor(acc, 1);
  acc += o;
  if ((tid & 1) == 0) {
    const size_t bh = (size_t)(b * 8 + h) << 12;
    int v = tid >> 1;
    if (v == 0) {
      corrN[bh + (T << 6)] = 0.f;          // tau==0 mod 64: no negative part
    } else {
      int d = v - 64;
      int tau = ((T << 6) + d) & 4095;
      if (d >= 0) corrP[bh + tau] = acc;
      else        corrN[bh + tau] = acc;
    }
  }
}

// ---------------------------------------------------------------------------
// Top-8 + softmax per (b,h). corr = corrP + corrN. Lowest-index tie-break.
// ---------------------------------------------------------------------------
__global__ __launch_bounds__(256) void topk_softmax(
    const float* __restrict__ corrP, const float* __restrict__ corrN,
    float* __restrict__ tw, int* __restrict__ ti)
{
  __shared__ float vals[4096];
  __shared__ float wvv[4]; __shared__ int wii[4];
  __shared__ float rv[8]; __shared__ int ri[8];
  const int tid = threadIdx.x;
  const int bh = blockIdx.x;
  const float* cp = corrP + (size_t)bh * 4096;
  const float* cn = corrN + (size_t)bh * 4096;
  for (int i = tid; i < 4096; i += 256) vals[i] = cp[i] + cn[i];
  __syncthreads();

  for (int it = 0; it < 8; ++it) {
    float bv = -3.4e38f; int bi = 1 << 30;
    for (int i = tid; i < 4096; i += 256) {
      float v = vals[i];
      if (v > bv) { bv = v; bi = i; }
    }
    #pragma unroll
    for (int o = 32; o > 0; o >>= 1) {
      float ov = __shfl_down(bv, o);
      int   oi = __shfl_down(bi, o);
      if (ov > bv || (ov == bv && oi < bi)) { bv = ov; bi = oi; }
    }
    if ((tid & 63) == 0) { wvv[tid >> 6] = bv; wii[tid >> 6] = bi; }
    __syncthreads();
    if (tid == 0) {
      for (int k = 1; k < 4; ++k)
        if (wvv[k] > bv || (wvv[k] == bv && wii[k] < bi)) { bv = wvv[k]; bi = wii[k]; }
      rv[it] = bv; ri[it] = bi; vals[bi] = -3.4e38f;
    }
    __syncthreads();
  }

  if (tid == 0) {
    float m = rv[0] * (1.f / 64.f);          // corr_mean = corr/dk; rv[0] is max
    float e[8]; float s = 0.f;
    for (int k = 0; k < 8; ++k) { e[k] = expf(rv[k] * (1.f / 64.f) - m); s += e[k]; }
    float inv = 1.f / s;
    for (int k = 0; k < 8; ++k) { tw[bh * 8 + k] = e[k] * inv; ti[bh * 8 + k] = ri[k]; }
  }
}

// ---------------------------------------------------------------------------
// out[b,l,h*64+d] = sum_k tw[k] * V[b,(l+ti[k])%L, h*64+d], stored fp16.
// ---------------------------------------------------------------------------
__global__ __launch_bounds__(256) void gather_attn(
    const float* __restrict__ V, const float* __restrict__ tw,
    const int* __restrict__ ti, _Float16* __restrict__ outp)
{
  const int tid = threadIdx.x;
  const int d4 = tid & 127;
  const int r  = (blockIdx.x << 1) + (tid >> 7);
  const int b  = r >> 12, l = r & 4095;
  const int h  = d4 >> 4;
  const float* w8 = tw + (((b << 3) + h) << 3);
  const int*   i8 = ti + (((b << 3) + h) << 3);
  f32x4_t acc = (f32x4_t){0.f, 0.f, 0.f, 0.f};
  #pragma unroll
  for (int k = 0; k < 8; ++k) {
    int ls = (l + i8[k]) & 4095;
    f32x4_t v = *(const f32x4_t*)(V + (((size_t)(b << 12) + ls) << 9) + (d4 << 2));
    float wk = w8[k];
    acc += v * wk;
  }
  half4_t o;
  o[0] = (_Float16)acc[0]; o[1] = (_Float16)acc[1];
  o[2] = (_Float16)acc[2]; o[3] = (_Float16)acc[3];
  *(half4_t*)(outp + ((size_t)r << 9) + (d4 << 2)) = o;
}

// ---------------------------------------------------------------------------
// y = LayerNorm(xa + xb) * g + be   (one wave per 512-wide row)
// ---------------------------------------------------------------------------
__global__ __launch_bounds__(256) void ln_add(
    const float* __restrict__ xa, const float* __restrict__ xb,
    const float* __restrict__ g, const float* __restrict__ be,
    float* __restrict__ y)
{
  const int lane = threadIdx.x & 63;
  const int row  = (blockIdx.x << 2) + (threadIdx.x >> 6);
  const size_t base = (size_t)row << 9;
  const float* ar = xa + base + (lane << 3);
  const float* br = xb + base + (lane << 3);
  f32x4_t a0 = *(const f32x4_t*)ar,       a1 = *(const f32x4_t*)(ar + 4);
  f32x4_t b0 = *(const f32x4_t*)br,       b1 = *(const f32x4_t*)(br + 4);
  f32x4_t v0 = a0 + b0, v1 = a1 + b1;
  float s  = v0[0] + v0[1] + v0[2] + v0[3] + v1[0] + v1[1] + v1[2] + v1[3];
  float s2 = v0[0]*v0[0] + v0[1]*v0[1] + v0[2]*v0[2] + v0[3]*v0[3]
           + v1[0]*v1[0] + v1[1]*v1[1] + v1[2]*v1[2] + v1[3]*v1[3];
  #pragma unroll
  for (int o = 1; o < 64; o <<= 1) { s += __shfl_xor(s, o); s2 += __shfl_xor(s2, o); }
  float mu  = s * (1.f / 512.f);
  float var = s2 * (1.f / 512.f) - mu * mu;
  float rs  = rsqrtf(var + 1e-5f);
  const float* gr  = g  + (lane << 3);
  const float* ber = be + (lane << 3);
  f32x4_t g0 = *(const f32x4_t*)gr,  g1v = *(const f32x4_t*)(gr + 4);
  f32x4_t e0 = *(const f32x4_t*)ber, e1  = *(const f32x4_t*)(ber + 4);
  f32x4_t o0, o1;
  #pragma unroll
  for (int i = 0; i < 4; ++i) {
    o0[i] = (v0[i] - mu) * rs * g0[i]  + e0[i];
    o1[i] = (v1[i] - mu) * rs * g1v[i] + e1[i];
  }
  float* yr = y + base + (lane << 3);
  *(f32x4_t*)yr = o0; *(f32x4_t*)(yr + 4) = o1;
}

// ---------------------------------------------------------------------------
// Series decomposition: moving average window 25, edge-replicated.
// mode 1: write seasonal fp32 + fp16, trend fp32
// mode 2: write seasonal fp32 (d_out), trendOut += trend (trend1+trend2)
// ---------------------------------------------------------------------------
__global__ __launch_bounds__(256) void movavg_decomp(
    const float* __restrict__ y, float* __restrict__ seasF,
    _Float16* __restrict__ seasH, float* __restrict__ trendOut, int mode)
{
  __shared__ float T[152 * 64];
  const int lt = blockIdx.x, dc = blockIdx.y, b = blockIdx.z;
  const int l0 = lt << 7, d0 = dc << 6;
  const int tid = threadIdx.x;
  for (int idx = tid; idx < 152 * 16; idx += 256) {
    int rr = idx >> 4, c4 = idx & 15;
    int ls = l0 - 12 + rr;
    ls = ls < 0 ? 0 : (ls > 4095 ? 4095 : ls);
    *(f32x4_t*)&T[rr * 64 + (c4 << 2)] =
        *(const f32x4_t*)(y + (((size_t)(b << 12) + ls) << 9) + d0 + (c4 << 2));
  }
  __syncthreads();
  for (int idx = tid; idx < 128 * 16; idx += 256) {
    int rr = idx >> 4, c4 = idx & 15;
    f32x4_t s = (f32x4_t){0.f, 0.f, 0.f, 0.f};
    #pragma unroll
    for (int j = 0; j < 25; ++j) s += *(const f32x4_t*)&T[(rr + j) * 64 + (c4 << 2)];
    f32x4_t trend = s * (1.f / 25.f);
    f32x4_t ctr   = *(const f32x4_t*)&T[(rr + 12) * 64 + (c4 << 2)];
    f32x4_t seas  = ctr - trend;
    size_t gp = (((size_t)(b << 12) + l0 + rr) << 9) + d0 + (c4 << 2);
    if (mode == 1) {
      *(f32x4_t*)(seasF + gp) = seas;
      half4_t sh;
      sh[0] = (_Float16)seas[0]; sh[1] = (_Float16)seas[1];
      sh[2] = (_Float16)seas[2]; sh[3] = (_Float16)seas[3];
      *(half4_t*)(seasH + gp) = sh;
      *(f32x4_t*)(trendOut + gp) = trend;
    } else {
      *(f32x4_t*)(seasF + gp) = seas;
      f32x4_t t1 = *(const f32x4_t*)(trendOut + gp);
      t1 += trend;
      *(f32x4_t*)(trendOut + gp) = t1;
    }
  }
}

// ---------------------------------------------------------------------------
// Weight prep: dst[n,k] = (fp16) src[k,n]
// ---------------------------------------------------------------------------
__global__ __launch_bounds__(256) void transpose_w(
    const float* __restrict__ src, _Float16* __restrict__ dst, int Kd, int Nd)
{
  __shared__ float t[32][33];
  const int kb = blockIdx.x << 5, nb = blockIdx.y << 5;
  const int tx = threadIdx.x & 31, ty = threadIdx.x >> 5;
  #pragma unroll
  for (int r0 = 0; r0 < 32; r0 += 8)
    t[ty + r0][tx] = src[(size_t)(kb + ty + r0) * Nd + nb + tx];
  __syncthreads();
  #pragma unroll
  for (int r0 = 0; r0 < 32; r0 += 8)
    dst[(size_t)(nb + ty + r0) * Kd + kb + tx] = (_Float16)t[tx][ty + r0];
}

__global__ __launch_bounds__(256) void f32_to_f16v(
    const float* __restrict__ src, _Float16* __restrict__ dst, int n4)
{
  int i = blockIdx.x * 256 + threadIdx.x;
  if (i >= n4) return;
  f32x4_t v = *(const f32x4_t*)(src + ((size_t)i << 2));
  half4_t o;
  o[0] = (_Float16)v[0]; o[1] = (_Float16)v[1];
  o[2] = (_Float16)v[2]; o[3] = (_Float16)v[3];
  *(half4_t*)(dst + ((size_t)i << 2)) = o;
}

// ---------------------------------------------------------------------------
extern "C" void kernel_launch(void* const* d_in, const int* in_sizes, int n_in,
                              void* d_out, int out_size, void* d_ws, size_t ws_size,
                              hipStream_t stream)
{
  const float* x   = (const float*)d_in[0];
  const float* Wq  = (const float*)d_in[1];
  const float* bq  = (const float*)d_in[2];
  const float* Wk  = (const float*)d_in[3];
  const float* bk  = (const float*)d_in[4];
  const float* Wv  = (const float*)d_in[5];
  const float* bv  = (const float*)d_in[6];
  const float* Wo  = (const float*)d_in[7];
  const float* bo  = (const float*)d_in[8];
  const float* W1  = (const float*)d_in[9];
  const float* b1  = (const float*)d_in[10];
  const float* W2  = (const float*)d_in[11];
  const float* b2  = (const float*)d_in[12];
  const float* g1  = (const float*)d_in[13];
  const float* be1 = (const float*)d_in[14];
  const float* g2  = (const float*)d_in[15];
  const float* be2 = (const float*)d_in[16];

  char* ws = (char*)d_ws;
  constexpr size_t ME = 16384ull * 512ull;                 // 8,388,608 elems
  constexpr size_t OFF_X16  = 0;                           // 16.8 MB fp16
  constexpr size_t OFF_WQT  = OFF_X16 + 2 * ME;
  constexpr size_t OFF_WKT  = OFF_WQT + 512 * 512 * 2;
  constexpr size_t OFF_WVT  = OFF_WKT + 512 * 512 * 2;
  constexpr size_t OFF_WOT  = OFF_WVT + 512 * 512 * 2;
  constexpr size_t OFF_W1T  = OFF_WOT + 512 * 512 * 2;
  constexpr size_t OFF_W2T  = OFF_W1T + 2048 * 512 * 2;
  constexpr size_t OFF_Q16  = OFF_W2T + 2048 * 512 * 2;
  constexpr size_t OFF_K16  = OFF_Q16 + 2 * ME;
  constexpr size_t OFF_V32  = OFF_K16 + 2 * ME;
  constexpr size_t OFF_CORR = OFF_V32 + 4 * ME;            // 32*4096 fp32 (P)
  constexpr size_t OFF_TW   = OFF_CORR + 32 * 4096 * 4;
  constexpr size_t OFF_TI   = OFF_TW + 1024;
  constexpr size_t OFF_ATTN = OFF_TI + 1024;
  constexpr size_t OFF_H16  = OFF_ATTN + 4 * ME;
  // aliases (lifetime-disjoint reuse)
  constexpr size_t OFF_AIN16 = OFF_X16;   // attn gather out (x16 dead)
  constexpr size_t OFF_S116  = OFF_X16;   // seasonal1 fp16 (attn-in dead)
  constexpr size_t OFF_S132  = OFF_Q16;   // seasonal1 fp32 spans Q16+K16
  constexpr size_t OFF_Y1    = OFF_V32;   // V dead after gather
  constexpr size_t OFF_Y2    = OFF_V32;   // y1 dead after movavg1
  constexpr size_t OFF_FF    = OFF_ATTN;  // attn dead after ln1
  constexpr size_t OFF_CORRN = OFF_H16;   // corrN: H16 region dead until FFN1

  _Float16* X16 = (_Float16*)(ws + OFF_X16);
  _Float16* WQT = (_Float16*)(ws + OFF_WQT);
  _Float16* WKT = (_Float16*)(ws + OFF_WKT);
  _Float16* WVT = (_Float16*)(ws + OFF_WVT);
  _Float16* WOT = (_Float16*)(ws + OFF_WOT);
  _Float16* W1T = (_Float16*)(ws + OFF_W1T);
  _Float16* W2T = (_Float16*)(ws + OFF_W2T);
  _Float16* Q16 = (_Float16*)(ws + OFF_Q16);
  _Float16* K16 = (_Float16*)(ws + OFF_K16);
  float*    V32 = (float*)(ws + OFF_V32);
  float*    CORRP = (float*)(ws + OFF_CORR);
  float*    CORRN = (float*)(ws + OFF_CORRN);
  float*    TW  = (float*)(ws + OFF_TW);
  int*      TI  = (int*)(ws + OFF_TI);
  float*    ATTN= (float*)(ws + OFF_ATTN);
  _Float16* H16 = (_Float16*)(ws + OFF_H16);
  _Float16* AIN16 = (_Float16*)(ws + OFF_AIN16);
  _Float16* S116  = (_Float16*)(ws + OFF_S116);
  float*    S132  = (float*)(ws + OFF_S132);
  float*    Y1    = (float*)(ws + OFF_Y1);
  float*    Y2    = (float*)(ws + OFF_Y2);
  float*    FF    = (float*)(ws + OFF_FF);

  float* OUT_SEAS  = (float*)d_out;            // seasonal2
  float* OUT_TREND = (float*)d_out + ME;       // trend1 + trend2

  // --- prep ---
  f32_to_f16v<<<8192, 256, 0, stream>>>(x, X16, (int)(ME / 4));
  transpose_w<<<dim3(16, 16), 256, 0, stream>>>(Wq, WQT, 512, 512);
  transpose_w<<<dim3(16, 16), 256, 0, stream>>>(Wk, WKT, 512, 512);
  transpose_w<<<dim3(16, 16), 256, 0, stream>>>(Wv, WVT, 512, 512);
  transpose_w<<<dim3(16, 16), 256, 0, stream>>>(Wo, WOT, 512, 512);
  transpose_w<<<dim3(16, 64), 256, 0, stream>>>(W1, W1T, 512, 2048);
  transpose_w<<<dim3(64, 16), 256, 0, stream>>>(W2, W2T, 2048, 512);

  // --- projections ---
  gemm_f16k<true,  false><<<dim3(128, 4), 256, 0, stream>>>(X16, WQT, bq, Q16, 16384, 512, 512);
  gemm_f16k<true,  false><<<dim3(128, 4), 256, 0, stream>>>(X16, WKT, bk, K16, 16384, 512, 512);
  gemm_f16k<false, false><<<dim3(128, 4), 256, 0, stream>>>(X16, WVT, bv, V32, 16384, 512, 512);

  // --- autocorrelation ---
  corr_gram3<<<2048, 256, 0, stream>>>(Q16, K16, CORRP, CORRN);
  topk_softmax<<<32, 256, 0, stream>>>(CORRP, CORRN, TW, TI);
  gather_attn<<<8192, 256, 0, stream>>>(V32, TW, TI, AIN16);
  gemm_f16k<false, false><<<dim3(128, 4), 256, 0, stream>>>(AIN16, WOT, bo, ATTN, 16384, 512, 512);

  // --- LN1 + decomp1 ---
  ln_add<<<4096, 256, 0, stream>>>(x, ATTN, g1, be1, Y1);
  movavg_decomp<<<dim3(32, 8, 4), 256, 0, stream>>>(Y1, S132, S116, OUT_TREND, 1);

  // --- FFN ---
  gemm_f16k<true,  true ><<<dim3(128, 16), 256, 0, stream>>>(S116, W1T, b1, H16, 16384, 2048, 512);
  gemm_f16k<false, false><<<dim3(128, 4),  256, 0, stream>>>(H16, W2T, b2, FF, 16384, 512, 2048);

  // --- LN2 + decomp2 ---
  ln_add<<<4096, 256, 0, stream>>>(S132, FF, g2, be2, Y2);
  movavg_decomp<<<dim3(32, 8, 4), 256, 0, stream>>>(Y2, OUT_SEAS, (_Float16*)nullptr, OUT_TREND, 2);
}

// Round 4
// 515.567 us; speedup vs baseline: 2.1219x; 1.2343x over previous
//
#include <hip/hip_runtime.h>
#include <hip/hip_bf16.h>
#include <math.h>

// ---------------------------------------------------------------------------
// Autoformer encoder layer, MI355X (gfx950).
// B=4, L=4096, D=512, H=8, dk=64, F=2048, MA=25, top_k=8.
// All GEMMs in fp16 MFMA (16x16x32_f16), fp32 accumulate.
// ---------------------------------------------------------------------------

typedef _Float16 half8_t __attribute__((ext_vector_type(8)));
typedef _Float16 half4_t __attribute__((ext_vector_type(4)));
typedef float    f32x4_t __attribute__((ext_vector_type(4)));

__device__ __forceinline__ void gl_lds16(const _Float16* src, _Float16* dst) {
  __builtin_amdgcn_global_load_lds(
      (const __attribute__((address_space(1))) unsigned int*)(const void*)src,
      (__attribute__((address_space(3))) unsigned int*)(void*)dst, 16, 0, 0);
}

// ---------------------------------------------------------------------------
// Generic fp16 GEMM:  out[M,N] = A[M,K] @ Bt[N,K]^T + bias, optional GELU.
// 128x128 tile, BK=64, 256 threads (4 waves, 2x2), XOR-swizzled LDS.
// ---------------------------------------------------------------------------
template<bool OUT16, bool DOGELU>
__global__ __launch_bounds__(256) void gemm_f16k(
    const _Float16* __restrict__ A, const _Float16* __restrict__ Bt,
    const float* __restrict__ bias, void* __restrict__ outp,
    int M, int N, int K)
{
  __shared__ _Float16 As[128 * 64];
  __shared__ _Float16 Bs[128 * 64];
  const int tid = threadIdx.x, lane = tid & 63, w = tid >> 6;
  const int wr = w >> 1, wc = w & 1;
  const int m0 = blockIdx.x * 128, n0 = blockIdx.y * 128;

  f32x4_t acc[4][4];
  #pragma unroll
  for (int i = 0; i < 4; ++i)
    #pragma unroll
    for (int j = 0; j < 4; ++j) acc[i][j] = (f32x4_t){0.f, 0.f, 0.f, 0.f};

  const _Float16* Ab = A + (size_t)m0 * K;
  const _Float16* Bb = Bt + (size_t)n0 * K;

  for (int k0 = 0; k0 < K; k0 += 64) {
    #pragma unroll
    for (int q = 0; q < 4; ++q) {
      int off = ((w << 2) + q) << 10;            // byte offset of wave-issue
      int row = (off >> 7) + (lane >> 3);
      int sl  = (lane & 7) ^ (row & 7);          // logical k-slot for this phys slot
      gl_lds16(Ab + (size_t)row * K + k0 + (sl << 3), As + (off >> 1));
    }
    #pragma unroll
    for (int q = 0; q < 4; ++q) {
      int off = ((w << 2) + q) << 10;
      int row = (off >> 7) + (lane >> 3);
      int sl  = (lane & 7) ^ (row & 7);
      gl_lds16(Bb + (size_t)row * K + k0 + (sl << 3), Bs + (off >> 1));
    }
    __syncthreads();

    #pragma unroll
    for (int kk = 0; kk < 2; ++kk) {
      half8_t af[4], bf[4];
      #pragma unroll
      for (int mi = 0; mi < 4; ++mi) {
        int row = wr * 64 + mi * 16 + (lane & 15);
        int sl  = ((kk << 2) + (lane >> 4)) ^ (row & 7);
        af[mi] = *(const half8_t*)(As + row * 64 + (sl << 3));
      }
      #pragma unroll
      for (int ni = 0; ni < 4; ++ni) {
        int row = wc * 64 + ni * 16 + (lane & 15);
        int sl  = ((kk << 2) + (lane >> 4)) ^ (row & 7);
        bf[ni] = *(const half8_t*)(Bs + row * 64 + (sl << 3));
      }
      #pragma unroll
      for (int mi = 0; mi < 4; ++mi)
        #pragma unroll
        for (int ni = 0; ni < 4; ++ni)
          acc[mi][ni] = __builtin_amdgcn_mfma_f32_16x16x32_f16(
              af[mi], bf[ni], acc[mi][ni], 0, 0, 0);
    }
    __syncthreads();
  }

  float bvv[4];
  #pragma unroll
  for (int ni = 0; ni < 4; ++ni)
    bvv[ni] = bias[n0 + wc * 64 + ni * 16 + (lane & 15)];

  #pragma unroll
  for (int mi = 0; mi < 4; ++mi) {
    int rbase = m0 + wr * 64 + mi * 16 + ((lane >> 4) << 2);
    #pragma unroll
    for (int ni = 0; ni < 4; ++ni) {
      int col = n0 + wc * 64 + ni * 16 + (lane & 15);
      #pragma unroll
      for (int r = 0; r < 4; ++r) {
        float v = acc[mi][ni][r] + bvv[ni];
        if (DOGELU) v = 0.5f * v * (1.f + erff(v * 0.70710678118654752f));
        size_t idx = (size_t)(rbase + r) * N + col;
        if (OUT16) ((_Float16*)outp)[idx] = (_Float16)v;
        else       ((float*)outp)[idx]    = v;
      }
    }
  }
}

// ---------------------------------------------------------------------------
// Autocorrelation v4: block owns (b, h, tau-window [64T, 64T+64)).
// tau = (64T + i - j) mod L is J-INDEPENDENT, so the 64x64 band tile is one
// 64x64x4096 GEMM: accumulate the Gram tile in registers across all 64
// J-tiles (2x2 wave quadrants), then scatter diagonal-major + extract ONCE.
// Per J: 8 ds_read_b128 + 8 MFMA + 1 barrier; double-buffered staging.
// Gd (34.8KB) aliases the stage buffers (loop-dead). No atomics.
// ---------------------------------------------------------------------------
__global__ __launch_bounds__(256) void corr_gram4(
    const _Float16* __restrict__ Q, const _Float16* __restrict__ Kt,
    float* __restrict__ corrP, float* __restrict__ corrN)
{
  __shared__ __attribute__((aligned(16))) char smem[34816];
  _Float16* Qs = (_Float16*)smem;             // [2][4096] halfs
  _Float16* Ks = (_Float16*)(smem + 16384);   // [2][4096] halfs
  float*    Gd = (float*)smem;                // [128][68] after loop

  const int tid = threadIdx.x, lane = tid & 63, w = tid >> 6;
  const int p  = blockIdx.x;
  const int lg = ((p & 7) << 8) + (p >> 3);   // XCD-chunked swizzle
  const int T = lg & 63, h = (lg >> 6) & 7, b = lg >> 9;
  const int qr = w >> 1, qc = w & 1;

  #define STAGE_Q(buf, tile) do {                                          \
    const size_t base_ = ((size_t)b * 4096 + (size_t)(tile) * 64) * 512 + h * 64; \
    _Pragma("unroll")                                                      \
    for (int q_ = 0; q_ < 2; ++q_) {                                       \
      int off_ = ((w << 1) + q_) << 10;                                    \
      int row_ = (off_ >> 7) + (lane >> 3);                                \
      int sl_  = (lane & 7) ^ (row_ & 7);                                  \
      gl_lds16(Q + base_ + (size_t)row_ * 512 + (sl_ << 3),                \
               Qs + (buf) * 4096 + (off_ >> 1));                           \
    } } while (0)
  #define STAGE_K(buf, tile) do {                                          \
    const size_t base_ = ((size_t)b * 4096 + (size_t)(tile) * 64) * 512 + h * 64; \
    _Pragma("unroll")                                                      \
    for (int q_ = 0; q_ < 2; ++q_) {                                       \
      int off_ = ((w << 1) + q_) << 10;                                    \
      int row_ = (off_ >> 7) + (lane >> 3);                                \
      int sl_  = (lane & 7) ^ (row_ & 7);                                  \
      gl_lds16(Kt + base_ + (size_t)row_ * 512 + (sl_ << 3),               \
               Ks + (buf) * 4096 + (off_ >> 1));                           \
    } } while (0)

  f32x4_t acc[2][2];
  #pragma unroll
  for (int i = 0; i < 2; ++i)
    #pragma unroll
    for (int j = 0; j < 2; ++j) acc[i][j] = (f32x4_t){0.f, 0.f, 0.f, 0.f};

  STAGE_Q(0, T);
  STAGE_K(0, 0);
  __syncthreads();                 // drains vmcnt -> buf0 ready

  int cur = 0;
  for (int J = 0; J < 64; ++J) {
    if (J < 63) {                  // async prefetch overlaps this J's compute
      STAGE_K(cur ^ 1, J + 1);
      STAGE_Q(cur ^ 1, (T + J + 1) & 63);
    }
    const _Float16* Qb = Qs + cur * 4096;
    const _Float16* Kb = Ks + cur * 4096;
    half8_t af[2][2], bf[2][2];
    #pragma unroll
    for (int mi = 0; mi < 2; ++mi) {
      int row = (qr << 5) + (mi << 4) + (lane & 15);
      #pragma unroll
      for (int kk = 0; kk < 2; ++kk) {
        int sl = ((kk << 2) + (lane >> 4)) ^ (row & 7);
        af[mi][kk] = *(const half8_t*)(Qb + row * 64 + (sl << 3));
      }
    }
    #pragma unroll
    for (int ni = 0; ni < 2; ++ni) {
      int row = (qc << 5) + (ni << 4) + (lane & 15);
      #pragma unroll
      for (int kk = 0; kk < 2; ++kk) {
        int sl = ((kk << 2) + (lane >> 4)) ^ (row & 7);
        bf[ni][kk] = *(const half8_t*)(Kb + row * 64 + (sl << 3));
      }
    }
    #pragma unroll
    for (int mi = 0; mi < 2; ++mi)
      #pragma unroll
      for (int ni = 0; ni < 2; ++ni) {
        acc[mi][ni] = __builtin_amdgcn_mfma_f32_16x16x32_f16(
            af[mi][0], bf[ni][0], acc[mi][ni], 0, 0, 0);
        acc[mi][ni] = __builtin_amdgcn_mfma_f32_16x16x32_f16(
            af[mi][1], bf[ni][1], acc[mi][ni], 0, 0, 0);
      }
    __syncthreads();               // frag reads done; prefetched tiles landed
    cur ^= 1;
  }
  #undef STAGE_Q
  #undef STAGE_K

  // ---- once-per-block diagonal extraction (Gd aliases stage buffers)
  for (int i = tid; i < 128 * 68; i += 256) Gd[i] = 0.f;
  __syncthreads();
  #pragma unroll
  for (int mi = 0; mi < 2; ++mi)
    #pragma unroll
    for (int ni = 0; ni < 2; ++ni)
      #pragma unroll
      for (int r = 0; r < 4; ++r) {
        int row = (qr << 5) + (mi << 4) + ((lane >> 4) << 2) + r;
        int col = (qc << 5) + (ni << 4) + (lane & 15);
        Gd[(row - col + 64) * 68 + col] = acc[mi][ni][r];
      }
  __syncthreads();

  float s;
  {
    const float* gp = &Gd[(tid >> 1) * 68 + ((tid & 1) << 5)];
    f32x4_t x0 = *(const f32x4_t*)gp        + *(const f32x4_t*)(gp + 4);
    f32x4_t x1 = *(const f32x4_t*)(gp + 8)  + *(const f32x4_t*)(gp + 12);
    f32x4_t x2 = *(const f32x4_t*)(gp + 16) + *(const f32x4_t*)(gp + 20);
    f32x4_t x3 = *(const f32x4_t*)(gp + 24) + *(const f32x4_t*)(gp + 28);
    x0 += x1; x2 += x3; x0 += x2;
    s = x0[0] + x0[1] + x0[2] + x0[3];
  }
  s += __shfl_xor(s, 1);
  if ((tid & 1) == 0) {
    const size_t bh = (size_t)(b * 8 + h) << 12;
    int v = tid >> 1;
    if (v == 0) {
      corrN[bh + (T << 6)] = 0.f;          // tau==0 mod 64: no negative part
    } else {
      int d = v - 64;
      int tau = ((T << 6) + d) & 4095;
      if (d >= 0) corrP[bh + tau] = s;
      else        corrN[bh + tau] = s;
    }
  }
}

// ---------------------------------------------------------------------------
// Top-8 + softmax per (b,h). corr = corrP + corrN. Lowest-index tie-break.
// ---------------------------------------------------------------------------
__global__ __launch_bounds__(256) void topk_softmax(
    const float* __restrict__ corrP, const float* __restrict__ corrN,
    float* __restrict__ tw, int* __restrict__ ti)
{
  __shared__ float vals[4096];
  __shared__ float wvv[4]; __shared__ int wii[4];
  __shared__ float rv[8]; __shared__ int ri[8];
  const int tid = threadIdx.x;
  const int bh = blockIdx.x;
  const float* cp = corrP + (size_t)bh * 4096;
  const float* cn = corrN + (size_t)bh * 4096;
  for (int i = tid; i < 4096; i += 256) vals[i] = cp[i] + cn[i];
  __syncthreads();

  for (int it = 0; it < 8; ++it) {
    float bv = -3.4e38f; int bi = 1 << 30;
    for (int i = tid; i < 4096; i += 256) {
      float v = vals[i];
      if (v > bv) { bv = v; bi = i; }
    }
    #pragma unroll
    for (int o = 32; o > 0; o >>= 1) {
      float ov = __shfl_down(bv, o);
      int   oi = __shfl_down(bi, o);
      if (ov > bv || (ov == bv && oi < bi)) { bv = ov; bi = oi; }
    }
    if ((tid & 63) == 0) { wvv[tid >> 6] = bv; wii[tid >> 6] = bi; }
    __syncthreads();
    if (tid == 0) {
      for (int k = 1; k < 4; ++k)
        if (wvv[k] > bv || (wvv[k] == bv && wii[k] < bi)) { bv = wvv[k]; bi = wii[k]; }
      rv[it] = bv; ri[it] = bi; vals[bi] = -3.4e38f;
    }
    __syncthreads();
  }

  if (tid == 0) {
    float m = rv[0] * (1.f / 64.f);          // corr_mean = corr/dk; rv[0] is max
    float e[8]; float s = 0.f;
    for (int k = 0; k < 8; ++k) { e[k] = expf(rv[k] * (1.f / 64.f) - m); s += e[k]; }
    float inv = 1.f / s;
    for (int k = 0; k < 8; ++k) { tw[bh * 8 + k] = e[k] * inv; ti[bh * 8 + k] = ri[k]; }
  }
}

// ---------------------------------------------------------------------------
// out[b,l,h*64+d] = sum_k tw[k] * V[b,(l+ti[k])%L, h*64+d]; V fp16 in, fp16 out.
// ---------------------------------------------------------------------------
__global__ __launch_bounds__(256) void gather_attn(
    const _Float16* __restrict__ V, const float* __restrict__ tw,
    const int* __restrict__ ti, _Float16* __restrict__ outp)
{
  const int tid = threadIdx.x;
  const int d4 = tid & 127;
  const int r  = (blockIdx.x << 1) + (tid >> 7);
  const int b  = r >> 12, l = r & 4095;
  const int h  = d4 >> 4;
  const float* w8 = tw + (((b << 3) + h) << 3);
  const int*   i8 = ti + (((b << 3) + h) << 3);
  f32x4_t acc = (f32x4_t){0.f, 0.f, 0.f, 0.f};
  #pragma unroll
  for (int k = 0; k < 8; ++k) {
    int ls = (l + i8[k]) & 4095;
    half4_t v = *(const half4_t*)(V + (((size_t)(b << 12) + ls) << 9) + (d4 << 2));
    float wk = w8[k];
    acc[0] += (float)v[0] * wk; acc[1] += (float)v[1] * wk;
    acc[2] += (float)v[2] * wk; acc[3] += (float)v[3] * wk;
  }
  half4_t o;
  o[0] = (_Float16)acc[0]; o[1] = (_Float16)acc[1];
  o[2] = (_Float16)acc[2]; o[3] = (_Float16)acc[3];
  *(half4_t*)(outp + ((size_t)r << 9) + (d4 << 2)) = o;
}

// ---------------------------------------------------------------------------
// y = LayerNorm(xa + xb) * g + be   (one wave per 512-wide row)
// ---------------------------------------------------------------------------
__global__ __launch_bounds__(256) void ln_add(
    const float* __restrict__ xa, const float* __restrict__ xb,
    const float* __restrict__ g, const float* __restrict__ be,
    float* __restrict__ y)
{
  const int lane = threadIdx.x & 63;
  const int row  = (blockIdx.x << 2) + (threadIdx.x >> 6);
  const size_t base = (size_t)row << 9;
  const float* ar = xa + base + (lane << 3);
  const float* br = xb + base + (lane << 3);
  f32x4_t a0 = *(const f32x4_t*)ar,       a1 = *(const f32x4_t*)(ar + 4);
  f32x4_t b0 = *(const f32x4_t*)br,       b1 = *(const f32x4_t*)(br + 4);
  f32x4_t v0 = a0 + b0, v1 = a1 + b1;
  float s  = v0[0] + v0[1] + v0[2] + v0[3] + v1[0] + v1[1] + v1[2] + v1[3];
  float s2 = v0[0]*v0[0] + v0[1]*v0[1] + v0[2]*v0[2] + v0[3]*v0[3]
           + v1[0]*v1[0] + v1[1]*v1[1] + v1[2]*v1[2] + v1[3]*v1[3];
  #pragma unroll
  for (int o = 1; o < 64; o <<= 1) { s += __shfl_xor(s, o); s2 += __shfl_xor(s2, o); }
  float mu  = s * (1.f / 512.f);
  float var = s2 * (1.f / 512.f) - mu * mu;
  float rs  = rsqrtf(var + 1e-5f);
  const float* gr  = g  + (lane << 3);
  const float* ber = be + (lane << 3);
  f32x4_t g0 = *(const f32x4_t*)gr,  g1v = *(const f32x4_t*)(gr + 4);
  f32x4_t e0 = *(const f32x4_t*)ber, e1  = *(const f32x4_t*)(ber + 4);
  f32x4_t o0, o1;
  #pragma unroll
  for (int i = 0; i < 4; ++i) {
    o0[i] = (v0[i] - mu) * rs * g0[i]  + e0[i];
    o1[i] = (v1[i] - mu) * rs * g1v[i] + e1[i];
  }
  float* yr = y + base + (lane << 3);
  *(f32x4_t*)yr = o0; *(f32x4_t*)(yr + 4) = o1;
}

// ---------------------------------------------------------------------------
// Series decomposition: moving average window 25, edge-replicated.
// mode 1: write seasonal fp32 + fp16, trend fp32
// mode 2: write seasonal fp32 (d_out), trendOut += trend (trend1+trend2)
// ---------------------------------------------------------------------------
__global__ __launch_bounds__(256) void movavg_decomp(
    const float* __restrict__ y, float* __restrict__ seasF,
    _Float16* __restrict__ seasH, float* __restrict__ trendOut, int mode)
{
  __shared__ float T[152 * 64];
  const int lt = blockIdx.x, dc = blockIdx.y, b = blockIdx.z;
  const int l0 = lt << 7, d0 = dc << 6;
  const int tid = threadIdx.x;
  for (int idx = tid; idx < 152 * 16; idx += 256) {
    int rr = idx >> 4, c4 = idx & 15;
    int ls = l0 - 12 + rr;
    ls = ls < 0 ? 0 : (ls > 4095 ? 4095 : ls);
    *(f32x4_t*)&T[rr * 64 + (c4 << 2)] =
        *(const f32x4_t*)(y + (((size_t)(b << 12) + ls) << 9) + d0 + (c4 << 2));
  }
  __syncthreads();
  for (int idx = tid; idx < 128 * 16; idx += 256) {
    int rr = idx >> 4, c4 = idx & 15;
    f32x4_t s = (f32x4_t){0.f, 0.f, 0.f, 0.f};
    #pragma unroll
    for (int j = 0; j < 25; ++j) s += *(const f32x4_t*)&T[(rr + j) * 64 + (c4 << 2)];
    f32x4_t trend = s * (1.f / 25.f);
    f32x4_t ctr   = *(const f32x4_t*)&T[(rr + 12) * 64 + (c4 << 2)];
    f32x4_t seas  = ctr - trend;
    size_t gp = (((size_t)(b << 12) + l0 + rr) << 9) + d0 + (c4 << 2);
    if (mode == 1) {
      *(f32x4_t*)(seasF + gp) = seas;
      half4_t sh;
      sh[0] = (_Float16)seas[0]; sh[1] = (_Float16)seas[1];
      sh[2] = (_Float16)seas[2]; sh[3] = (_Float16)seas[3];
      *(half4_t*)(seasH + gp) = sh;
      *(f32x4_t*)(trendOut + gp) = trend;
    } else {
      *(f32x4_t*)(seasF + gp) = seas;
      f32x4_t t1 = *(const f32x4_t*)(trendOut + gp);
      t1 += trend;
      *(f32x4_t*)(trendOut + gp) = t1;
    }
  }
}

// ---------------------------------------------------------------------------
// Weight prep, all 6 in one dispatch: dst[n,k] = (fp16) src[k,n]
// ---------------------------------------------------------------------------
__global__ __launch_bounds__(256) void transpose_all(
    const float* __restrict__ Wq, const float* __restrict__ Wk,
    const float* __restrict__ Wv, const float* __restrict__ Wo,
    const float* __restrict__ W1, const float* __restrict__ W2,
    _Float16* __restrict__ WQT, _Float16* __restrict__ WKT,
    _Float16* __restrict__ WVT, _Float16* __restrict__ WOT,
    _Float16* __restrict__ W1T, _Float16* __restrict__ W2T)
{
  const int id = blockIdx.x;
  const float* src; _Float16* dst; int Kd, Nd, kb, nb;
  if (id < 1024) {
    int wsel = id >> 8, r = id & 255;
    kb = (r & 15) << 5; nb = (r >> 4) << 5; Kd = 512; Nd = 512;
    src = wsel == 0 ? Wq : wsel == 1 ? Wk : wsel == 2 ? Wv : Wo;
    dst = wsel == 0 ? WQT : wsel == 1 ? WKT : wsel == 2 ? WVT : WOT;
  } else if (id < 2048) {
    int r = id - 1024;
    kb = (r & 15) << 5; nb = (r >> 4) << 5; Kd = 512; Nd = 2048;
    src = W1; dst = W1T;
  } else {
    int r = id - 2048;
    kb = (r & 63) << 5; nb = (r >> 6) << 5; Kd = 2048; Nd = 512;
    src = W2; dst = W2T;
  }
  __shared__ float t[32][33];
  const int tx = threadIdx.x & 31, ty = threadIdx.x >> 5;
  #pragma unroll
  for (int r0 = 0; r0 < 32; r0 += 8)
    t[ty + r0][tx] = src[(size_t)(kb + ty + r0) * Nd + nb + tx];
  __syncthreads();
  #pragma unroll
  for (int r0 = 0; r0 < 32; r0 += 8)
    dst[(size_t)(nb + ty + r0) * Kd + kb + tx] = (_Float16)t[tx][ty + r0];
}

__global__ __launch_bounds__(256) void f32_to_f16v(
    const float* __restrict__ src, _Float16* __restrict__ dst, int n4)
{
  int i = blockIdx.x * 256 + threadIdx.x;
  if (i >= n4) return;
  f32x4_t v = *(const f32x4_t*)(src + ((size_t)i << 2));
  half4_t o;
  o[0] = (_Float16)v[0]; o[1] = (_Float16)v[1];
  o[2] = (_Float16)v[2]; o[3] = (_Float16)v[3];
  *(half4_t*)(dst + ((size_t)i << 2)) = o;
}

// ---------------------------------------------------------------------------
extern "C" void kernel_launch(void* const* d_in, const int* in_sizes, int n_in,
                              void* d_out, int out_size, void* d_ws, size_t ws_size,
                              hipStream_t stream)
{
  const float* x   = (const float*)d_in[0];
  const float* Wq  = (const float*)d_in[1];
  const float* bq  = (const float*)d_in[2];
  const float* Wk  = (const float*)d_in[3];
  const float* bk  = (const float*)d_in[4];
  const float* Wv  = (const float*)d_in[5];
  const float* bv  = (const float*)d_in[6];
  const float* Wo  = (const float*)d_in[7];
  const float* bo  = (const float*)d_in[8];
  const float* W1  = (const float*)d_in[9];
  const float* b1  = (const float*)d_in[10];
  const float* W2  = (const float*)d_in[11];
  const float* b2  = (const float*)d_in[12];
  const float* g1  = (const float*)d_in[13];
  const float* be1 = (const float*)d_in[14];
  const float* g2  = (const float*)d_in[15];
  const float* be2 = (const float*)d_in[16];

  char* ws = (char*)d_ws;
  constexpr size_t ME = 16384ull * 512ull;                 // 8,388,608 elems
  constexpr size_t OFF_X16  = 0;                           // 16.8 MB fp16
  constexpr size_t OFF_WQT  = OFF_X16 + 2 * ME;
  constexpr size_t OFF_WKT  = OFF_WQT + 512 * 512 * 2;
  constexpr size_t OFF_WVT  = OFF_WKT + 512 * 512 * 2;
  constexpr size_t OFF_WOT  = OFF_WVT + 512 * 512 * 2;
  constexpr size_t OFF_W1T  = OFF_WOT + 512 * 512 * 2;
  constexpr size_t OFF_W2T  = OFF_W1T + 2048 * 512 * 2;
  constexpr size_t OFF_Q16  = OFF_W2T + 2048 * 512 * 2;
  constexpr size_t OFF_K16  = OFF_Q16 + 2 * ME;
  constexpr size_t OFF_V16  = OFF_K16 + 2 * ME;            // fp16 V (region 4*ME for Y alias)
  constexpr size_t OFF_CORR = OFF_V16 + 4 * ME;            // 32*4096 fp32 (P)
  constexpr size_t OFF_TW   = OFF_CORR + 32 * 4096 * 4;
  constexpr size_t OFF_TI   = OFF_TW + 1024;
  constexpr size_t OFF_ATTN = OFF_TI + 1024;
  constexpr size_t OFF_H16  = OFF_ATTN + 4 * ME;
  // aliases (lifetime-disjoint reuse)
  constexpr size_t OFF_AIN16 = OFF_X16;   // attn gather out (x16 dead)
  constexpr size_t OFF_S116  = OFF_X16;   // seasonal1 fp16 (attn-in dead)
  constexpr size_t OFF_S132  = OFF_Q16;   // seasonal1 fp32 spans Q16+K16
  constexpr size_t OFF_Y1    = OFF_V16;   // V dead after gather
  constexpr size_t OFF_Y2    = OFF_V16;   // y1 dead after movavg1
  constexpr size_t OFF_FF    = OFF_ATTN;  // attn dead after ln1
  constexpr size_t OFF_CORRN = OFF_H16;   // corrN: H16 region dead until FFN1

  _Float16* X16 = (_Float16*)(ws + OFF_X16);
  _Float16* WQT = (_Float16*)(ws + OFF_WQT);
  _Float16* WKT = (_Float16*)(ws + OFF_WKT);
  _Float16* WVT = (_Float16*)(ws + OFF_WVT);
  _Float16* WOT = (_Float16*)(ws + OFF_WOT);
  _Float16* W1T = (_Float16*)(ws + OFF_W1T);
  _Float16* W2T = (_Float16*)(ws + OFF_W2T);
  _Float16* Q16 = (_Float16*)(ws + OFF_Q16);
  _Float16* K16 = (_Float16*)(ws + OFF_K16);
  _Float16* V16 = (_Float16*)(ws + OFF_V16);
  float*    CORRP = (float*)(ws + OFF_CORR);
  float*    CORRN = (float*)(ws + OFF_CORRN);
  float*    TW  = (float*)(ws + OFF_TW);
  int*      TI  = (int*)(ws + OFF_TI);
  float*    ATTN= (float*)(ws + OFF_ATTN);
  _Float16* H16 = (_Float16*)(ws + OFF_H16);
  _Float16* AIN16 = (_Float16*)(ws + OFF_AIN16);
  _Float16* S116  = (_Float16*)(ws + OFF_S116);
  float*    S132  = (float*)(ws + OFF_S132);
  float*    Y1    = (float*)(ws + OFF_Y1);
  float*    Y2    = (float*)(ws + OFF_Y2);
  float*    FF    = (float*)(ws + OFF_FF);

  float* OUT_SEAS  = (float*)d_out;            // seasonal2
  float* OUT_TREND = (float*)d_out + ME;       // trend1 + trend2

  // --- prep ---
  f32_to_f16v<<<8192, 256, 0, stream>>>(x, X16, (int)(ME / 4));
  transpose_all<<<3072, 256, 0, stream>>>(Wq, Wk, Wv, Wo, W1, W2,
                                          WQT, WKT, WVT, WOT, W1T, W2T);

  // --- projections ---
  gemm_f16k<true,  false><<<dim3(128, 4), 256, 0, stream>>>(X16, WQT, bq, Q16, 16384, 512, 512);
  gemm_f16k<true,  false><<<dim3(128, 4), 256, 0, stream>>>(X16, WKT, bk, K16, 16384, 512, 512);
  gemm_f16k<true,  false><<<dim3(128, 4), 256, 0, stream>>>(X16, WVT, bv, V16, 16384, 512, 512);

  // --- autocorrelation ---
  corr_gram4<<<2048, 256, 0, stream>>>(Q16, K16, CORRP, CORRN);
  topk_softmax<<<32, 256, 0, stream>>>(CORRP, CORRN, TW, TI);
  gather_attn<<<8192, 256, 0, stream>>>(V16, TW, TI, AIN16);
  gemm_f16k<false, false><<<dim3(128, 4), 256, 0, stream>>>(AIN16, WOT, bo, ATTN, 16384, 512, 512);

  // --- LN1 + decomp1 ---
  ln_add<<<4096, 256, 0, stream>>>(x, ATTN, g1, be1, Y1);
  movavg_decomp<<<dim3(32, 8, 4), 256, 0, stream>>>(Y1, S132, S116, OUT_TREND, 1);

  // --- FFN ---
  gemm_f16k<true,  true ><<<dim3(128, 16), 256, 0, stream>>>(S116, W1T, b1, H16, 16384, 2048, 512);
  gemm_f16k<false, false><<<dim3(128, 4),  256, 0, stream>>>(H16, W2T, b2, FF, 16384, 512, 2048);

  // --- LN2 + decomp2 ---
  ln_add<<<4096, 256, 0, stream>>>(S132, FF, g2, be2, Y2);
  movavg_decomp<<<dim3(32, 8, 4), 256, 0, stream>>>(Y2, OUT_SEAS, (_Float16*)nullptr, OUT_TREND, 2);
}